// Round 4
// baseline (366.746 us; speedup 1.0000x reference)
//
#include <hip/hip_runtime.h>
#include <hip/hip_bf16.h>

typedef short s16x8 __attribute__((ext_vector_type(8)));
typedef short s16x4 __attribute__((ext_vector_type(4)));
typedef float f32x4 __attribute__((ext_vector_type(4)));
typedef unsigned u32;
typedef u32 u32x2 __attribute__((ext_vector_type(2)));

#define DI __device__ __forceinline__

constexpr int BB = 16;    // batch
constexpr int CC = 256;   // in channels
constexpr int MM = 4096;  // H*W
constexpr int KD = 16;    // k
constexpr int UK = 64;    // u*k
constexpr float EPSV = 1e-5f;

DI unsigned short f2bf(float f) {
  union { float f; unsigned u; } v; v.f = f;
  unsigned r = v.u + 0x7FFFu + ((v.u >> 16) & 1u);
  return (unsigned short)(r >> 16);
}
DI float bflo(u32 v) { union { u32 u; float f; } w; w.u = v << 16; return w.f; }
DI float bfhi(u32 v) { union { u32 u; float f; } w; w.u = v & 0xFFFF0000u; return w.f; }

// ---- fused: x f32 -> bf16 (global XBF + LDS), xsum, G-partial via MFMA ----
// grid 256 = (b, mc); block 512 thr; LDS = full 256x256 bf16 tile (pitch 264)
__global__ __launch_bounds__(512) void k_cvt_g(const float* __restrict__ x,
    unsigned short* __restrict__ xbf, float* __restrict__ xsum,
    u32* __restrict__ part) {
  int b = blockIdx.x >> 4, mc = blockIdx.x & 15;
  int m0 = mc * 256;
  __shared__ short lt[256 * 264];
  int t = threadIdx.x, w = t >> 6, l = t & 63;

  // load f32 -> convert -> store bf16 global + LDS, accumulate xsum
  for (int i = 0; i < 32; ++i) {
    int row = i * 8 + w;
    size_t gidx = ((size_t)(b * CC + row)) * MM + m0 + l * 4;
    float4 v = *(const float4*)(x + gidx);
    s16x4 c;
    c[0] = (short)f2bf(v.x); c[1] = (short)f2bf(v.y);
    c[2] = (short)f2bf(v.z); c[3] = (short)f2bf(v.w);
    *(s16x4*)&xbf[gidx] = c;
    *(s16x4*)&lt[row * 264 + l * 4] = c;
    float s = v.x + v.y + v.z + v.w;
#pragma unroll
    for (int o = 32; o; o >>= 1) s += __shfl_down(s, o);
    if (l == 0) atomicAdd(&xsum[row], s);
  }
  __syncthreads();

  // MFMA phase: G-partial over this block's 256 m-columns
  int wr = w >> 2, wc = w & 3;
  int lrow = l & 15, lk8 = (l >> 4) * 8;
  f32x4 acc[8][4];
#pragma unroll
  for (int i = 0; i < 8; ++i)
#pragma unroll
    for (int j = 0; j < 4; ++j) acc[i][j] = (f32x4)0.f;

#pragma unroll
  for (int ks = 0; ks < 8; ++ks) {
    s16x8 af[8], bf[4];
#pragma unroll
    for (int i = 0; i < 8; ++i)
      af[i] = *(const s16x8*)&lt[(wr * 128 + i * 16 + lrow) * 264 + ks * 32 + lk8];
#pragma unroll
    for (int j = 0; j < 4; ++j)
      bf[j] = *(const s16x8*)&lt[(wc * 64 + j * 16 + lrow) * 264 + ks * 32 + lk8];
#pragma unroll
    for (int i = 0; i < 8; ++i)
#pragma unroll
      for (int j = 0; j < 4; ++j)
        acc[i][j] = __builtin_amdgcn_mfma_f32_16x16x32_bf16(af[i], bf[j], acc[i][j], 0, 0, 0);
  }

  // epilogue: packed bf16 partial, lane-minor flat layout (coalesced 512B/wave)
  size_t pb = (size_t)blockIdx.x * 32768;
#pragma unroll
  for (int i = 0; i < 8; ++i)
#pragma unroll
    for (int j = 0; j < 4; ++j) {
      int tau = (w * 8 + i) * 4 + j;
      u32x2 pk;
      pk[0] = (u32)f2bf(acc[i][j][0]) | ((u32)f2bf(acc[i][j][1]) << 16);
      pk[1] = (u32)f2bf(acc[i][j][2]) | ((u32)f2bf(acc[i][j][3]) << 16);
      *(u32x2*)&part[pb + tau * 128 + l * 2] = pk;
    }
}

// ---- reduce 256 G-partials -> G ----
__global__ __launch_bounds__(256) void k_gred(const u32* __restrict__ part,
                                              float* __restrict__ G) {
  int q = blockIdx.x * 256 + threadIdx.x;   // 0..32767
  float s0 = 0.f, s1 = 0.f;
#pragma unroll 8
  for (int p = 0; p < 256; ++p) {
    u32 v = part[(size_t)p * 32768 + q];
    s0 += bflo(v);
    s1 += bfhi(v);
  }
  int r2 = q & 1, l = (q >> 1) & 63, tau = q >> 7;
  int j = tau & 3, i = (tau >> 2) & 7, w = tau >> 5;
  int wr = w >> 2, wc = w & 3;
  int row = wr * 128 + i * 16 + (l >> 4) * 4 + r2 * 2;
  int col = wc * 64 + j * 16 + (l & 15);
  G[row * 256 + col] = s0;
  G[(row + 1) * 256 + col] = s1;
}

// ---------------- Q/K projection via bf16 MFMA (reads bf16 x) ----------------
__global__ __launch_bounds__(256) void k_proj(const unsigned short* __restrict__ xbf,
    const float* __restrict__ Wq, const float* __restrict__ bq,
    const float* __restrict__ Wk, const float* __restrict__ bk,
    float* __restrict__ Kb, float* __restrict__ Qb) {
  int b = blockIdx.x >> 5, mc = blockIdx.x & 31;   // 16 b * 32 m-chunks
  int gm0 = mc * 128;
  __shared__ short wlds[80 * 264];                 // W bf16, pitch 264
  __shared__ u32 xt[128 * 17];                     // x^T tile: [m][c-pair], pitch 17
  int t = threadIdx.x;
  int w = t >> 6, l = t & 63;
  int lrow = l & 15, lk = l >> 4;                  // lk in 0..3

#pragma unroll 4
  for (int o = 0; o < 80; ++o) {
    float v = (o < 64) ? Wk[o * CC + t] : Wq[(o - 64) * CC + t];
    wlds[o * 264 + t] = (short)f2bf(v);
  }

  f32x4 acc[5][2];
#pragma unroll
  for (int i = 0; i < 5; ++i) { acc[i][0] = (f32x4)0.f; acc[i][1] = (f32x4)0.f; }

  int c2 = t >> 4;          // c-pair column 0..15
  int mq = t & 15;          // m quad index

  for (int ks = 0; ks < 8; ++ks) {
    int c0 = ks * 32;
    __syncthreads();
#pragma unroll
    for (int mb = 0; mb < 128; mb += 64) {
      int m = mb + mq * 4;
      const unsigned short* p0 = xbf + ((size_t)(b * CC + c0 + 2 * c2)) * MM + gm0 + m;
      s16x4 v0 = *(const s16x4*)p0;
      s16x4 v1 = *(const s16x4*)(p0 + MM);
      xt[(m + 0) * 17 + c2] = (u32)(unsigned short)v0[0] | ((u32)(unsigned short)v1[0] << 16);
      xt[(m + 1) * 17 + c2] = (u32)(unsigned short)v0[1] | ((u32)(unsigned short)v1[1] << 16);
      xt[(m + 2) * 17 + c2] = (u32)(unsigned short)v0[2] | ((u32)(unsigned short)v1[2] << 16);
      xt[(m + 3) * 17 + c2] = (u32)(unsigned short)v0[3] | ((u32)(unsigned short)v1[3] << 16);
    }
    __syncthreads();
    union { s16x8 v; u32 wd[4]; } bfr[2];
#pragma unroll
    for (int j = 0; j < 2; ++j) {
      int ml = w * 32 + j * 16 + lrow;
#pragma unroll
      for (int i = 0; i < 4; ++i) bfr[j].wd[i] = xt[ml * 17 + lk * 4 + i];
    }
#pragma unroll
    for (int ot = 0; ot < 5; ++ot) {
      s16x8 af = *(const s16x8*)&wlds[(ot * 16 + lrow) * 264 + c0 + lk * 8];
      acc[ot][0] = __builtin_amdgcn_mfma_f32_16x16x32_bf16(af, bfr[0].v, acc[ot][0], 0, 0, 0);
      acc[ot][1] = __builtin_amdgcn_mfma_f32_16x16x32_bf16(af, bfr[1].v, acc[ot][1], 0, 0, 0);
    }
  }

#pragma unroll
  for (int ot = 0; ot < 5; ++ot)
#pragma unroll
    for (int j = 0; j < 2; ++j)
#pragma unroll
      for (int r = 0; r < 4; ++r) {
        int o = ot * 16 + lk * 4 + r;
        int m = gm0 + w * 32 + j * 16 + lrow;
        float val = acc[ot][j][r];
        if (o < 64) Kb[((size_t)(b * UK + o)) * MM + m] = val + bk[o];
        else        Qb[((size_t)(b * KD + o - 64)) * MM + m] = val + bq[o - 64];
      }
}

// ---------------- softmax row stats over K ----------------
__global__ __launch_bounds__(256) void k_sstats(const float* __restrict__ Kb,
    float* __restrict__ rmax, float* __restrict__ rsum) {
  int r = blockIdx.x;                    // 0..1023
  int t = threadIdx.x;
  const float4* p = (const float4*)(Kb + (size_t)r * MM);
  float4 v[4];
  float mx = -3.4e38f;
#pragma unroll
  for (int i = 0; i < 4; ++i) {
    v[i] = p[i * 256 + t];
    mx = fmaxf(mx, fmaxf(fmaxf(v[i].x, v[i].y), fmaxf(v[i].z, v[i].w)));
  }
#pragma unroll
  for (int o = 32; o; o >>= 1) mx = fmaxf(mx, __shfl_xor(mx, o));
  __shared__ float red[4];
  int w = t >> 6;
  if ((t & 63) == 0) red[w] = mx;
  __syncthreads();
  mx = fmaxf(fmaxf(red[0], red[1]), fmaxf(red[2], red[3]));
  float s = 0.f;
#pragma unroll
  for (int i = 0; i < 4; ++i)
    s += __expf(v[i].x - mx) + __expf(v[i].y - mx) +
         __expf(v[i].z - mx) + __expf(v[i].w - mx);
#pragma unroll
  for (int o = 32; o; o >>= 1) s += __shfl_xor(s, o);
  __syncthreads();
  if ((t & 63) == 0) red[w] = s;
  __syncthreads();
  if (t == 0) {
    rmax[r] = mx;
    rsum[r] = red[0] + red[1] + red[2] + red[3];
  }
}

// ---------------- BN affine params from G, xsum ----------------
__global__ __launch_bounds__(256) void k_fin(const float* __restrict__ G,
    const float* __restrict__ xsum,
    const float* __restrict__ Wv, const float* __restrict__ bv,
    const float* __restrict__ gv, const float* __restrict__ btv,
    const float* __restrict__ Wq, const float* __restrict__ bq,
    const float* __restrict__ gq, const float* __restrict__ btq,
    float* __restrict__ AV, float* __restrict__ BVa,
    float* __restrict__ AQ, float* __restrict__ BQa) {
  int o = blockIdx.x;                    // 0..1039: 0..1023 V-ch, 1024.. Q-ch
  int t = threadIdx.x;
  const float* w; float bias, gamma, beta; float* pa; float* pb;
  if (o < 1024) {
    w = Wv + (size_t)o * CC; bias = bv[o]; gamma = gv[o]; beta = btv[o];
    pa = AV + o; pb = BVa + o;
  } else {
    int oi = o - 1024;
    w = Wq + (size_t)oi * CC; bias = bq[oi]; gamma = gq[oi]; beta = btq[oi];
    pa = AQ + oi; pb = BQa + oi;
  }
  __shared__ float lw[256];
  lw[t] = w[t];
  __syncthreads();
  const float* g = G + (size_t)t * CC;
  float tv = 0.f;
#pragma unroll 8
  for (int c = 0; c < CC; c += 4) {
    float4 g4 = *(const float4*)(g + c);
    tv += g4.x * lw[c] + g4.y * lw[c + 1] + g4.z * lw[c + 2] + g4.w * lw[c + 3];
  }
  float qf = tv * lw[t];
  float sx = lw[t] * xsum[t];
#pragma unroll
  for (int od = 32; od; od >>= 1) { qf += __shfl_xor(qf, od); sx += __shfl_xor(sx, od); }
  __shared__ float r1[4], r2[4];
  int wv = t >> 6;
  if ((t & 63) == 0) { r1[wv] = qf; r2[wv] = sx; }
  __syncthreads();
  if (t == 0) {
    qf = r1[0] + r1[1] + r1[2] + r1[3];
    sx = r2[0] + r2[1] + r2[2] + r2[3];
    const float invN = 1.f / 65536.f;
    float mean = sx * invN + bias;
    float e2 = qf * invN + 2.f * bias * sx * invN + bias * bias;
    float var = e2 - mean * mean;
    float a = gamma * rsqrtf(var + EPSV);
    *pa = a;
    *pb = beta - mean * a;
  }
}

// ---------------- xp[b,j,c] = sum_m exp(K[b,j,m]-rmax) * x[b,c,m] ----------------
__global__ __launch_bounds__(256) void k_xp(const unsigned short* __restrict__ xbf,
    const float* __restrict__ Kb, const float* __restrict__ rmax,
    float* __restrict__ XP) {
  int b = blockIdx.x >> 3, kc = blockIdx.x & 7;
  int kbase = kc * 512;
  __shared__ short la[64][40];
  __shared__ short lb[256][40];
  int t = threadIdx.x, w = t >> 6, l = t & 63;
  int lrow = l & 15, lk = (l >> 4) * 8;

  f32x4 acc[4][4];
#pragma unroll
  for (int i = 0; i < 4; ++i)
#pragma unroll
    for (int j = 0; j < 4; ++j) acc[i][j] = (f32x4)0.f;

  for (int ks = 0; ks < 16; ++ks) {
    int k0 = kbase + ks * 32;
    __syncthreads();
    {   // stage A: exp(K - rmax), 64 rows x 32 (K is f32)
      int r = t >> 2, sg = (t & 3) * 8;
      const float4* src = (const float4*)(Kb + ((size_t)(b * UK + r)) * MM + k0 + sg);
      float rm = rmax[b * UK + r];
      s16x8 wv;
#pragma unroll
      for (int i = 0; i < 2; ++i) {
        float4 v = src[i];
        wv[i * 4 + 0] = (short)f2bf(__expf(v.x - rm));
        wv[i * 4 + 1] = (short)f2bf(__expf(v.y - rm));
        wv[i * 4 + 2] = (short)f2bf(__expf(v.z - rm));
        wv[i * 4 + 3] = (short)f2bf(__expf(v.w - rm));
      }
      *(s16x8*)&la[r][sg] = wv;
    }
#pragma unroll
    for (int i = 0; i < 4; ++i) {   // stage B: bf16 x, 256 rows x 32
      int r = i * 64 + (t >> 2), sg = (t & 3) * 8;
      s16x8 v = *(const s16x8*)&xbf[((size_t)(b * CC + r)) * MM + k0 + sg];
      *(s16x8*)&lb[r][sg] = v;
    }
    __syncthreads();
    s16x8 af[4], bfr[4];
#pragma unroll
    for (int i = 0; i < 4; ++i) af[i] = *(const s16x8*)&la[i * 16 + lrow][lk];
#pragma unroll
    for (int j = 0; j < 4; ++j) bfr[j] = *(const s16x8*)&lb[w * 64 + j * 16 + lrow][lk];
#pragma unroll
    for (int i = 0; i < 4; ++i)
#pragma unroll
      for (int j = 0; j < 4; ++j)
        acc[i][j] = __builtin_amdgcn_mfma_f32_16x16x32_bf16(af[i], bfr[j], acc[i][j], 0, 0, 0);
  }
#pragma unroll
  for (int i = 0; i < 4; ++i)
#pragma unroll
    for (int j = 0; j < 4; ++j)
#pragma unroll
      for (int r = 0; r < 4; ++r) {
        int row = i * 16 + (l >> 4) * 4 + r;       // j index 0..63
        int col = w * 64 + j * 16 + lrow;          // c index 0..255
        atomicAdd(&XP[((size_t)b * UK + row) * CC + col], acc[i][j][r]);
      }
}

// ---------------- ctx[b,kk,vv] = sum_u aV*(Wv . xp_n + bv) + bVa ----------------
__global__ __launch_bounds__(256) void k_ctx(const float* __restrict__ XP,
    const float* __restrict__ rsum,
    const float* __restrict__ Wv, const float* __restrict__ bv,
    const float* __restrict__ AV, const float* __restrict__ BVa,
    float* __restrict__ CTX) {
  int b = blockIdx.x >> 4, kk = blockIdx.x & 15;
  __shared__ float lxp[4][256];
  int t = threadIdx.x;
#pragma unroll
  for (int u = 0; u < 4; ++u) {
    int row = b * UK + u * KD + kk;
    lxp[u][t] = XP[(size_t)row * CC + t] / rsum[row];
  }
  __syncthreads();
  float acc = 0.f;
#pragma unroll
  for (int u = 0; u < 4; ++u) {
    int ch = u * 256 + t;
    const float4* wv4 = (const float4*)(Wv + (size_t)ch * CC);
    float dot = 0.f;
#pragma unroll 8
    for (int c4 = 0; c4 < 64; ++c4) {
      float4 wv = wv4[c4];
      dot += wv.x * lxp[u][c4 * 4 + 0] + wv.y * lxp[u][c4 * 4 + 1] +
             wv.z * lxp[u][c4 * 4 + 2] + wv.w * lxp[u][c4 * 4 + 3];
    }
    acc += AV[ch] * (dot + bv[ch]) + BVa[ch];
  }
  CTX[((size_t)b * KD + kk) * 256 + t] = acc;
}

// ---------------- y[b,vv,m] = sum_kk (aQ*Q+bQ)[kk,m] * ctx[kk,vv] ----------------
__global__ __launch_bounds__(256) void k_y(const float* __restrict__ Qb,
    const float* __restrict__ CTX,
    const float* __restrict__ AQ, const float* __restrict__ BQa,
    float* __restrict__ y) {
  int b = blockIdx.x >> 4, nc = blockIdx.x & 15;
  int m = nc * 256 + threadIdx.x;
  float qn[16];
#pragma unroll
  for (int kk = 0; kk < 16; ++kk)
    qn[kk] = AQ[kk] * Qb[((size_t)b * KD + kk) * MM + m] + BQa[kk];
  const float* cb = CTX + (size_t)b * KD * 256;
  float* yo = y + (size_t)b * 256 * MM + m;
#pragma unroll 4
  for (int vv = 0; vv < 256; ++vv) {
    float acc = 0.f;
#pragma unroll
    for (int kk = 0; kk < 16; ++kk)
      acc = fmaf(qn[kk], cb[kk * 256 + vv], acc);   // uniform -> scalar loads
    yo[(size_t)vv * MM] = acc;
  }
}

extern "C" void kernel_launch(void* const* d_in, const int* in_sizes, int n_in,
                              void* d_out, int out_size, void* d_ws, size_t ws_size,
                              hipStream_t stream) {
  const float* x   = (const float*)d_in[0];
  const float* Wq  = (const float*)d_in[1];
  const float* bq  = (const float*)d_in[2];
  const float* Wk  = (const float*)d_in[3];
  const float* bk  = (const float*)d_in[4];
  const float* Wv  = (const float*)d_in[5];
  const float* bv  = (const float*)d_in[6];
  const float* gq  = (const float*)d_in[7];
  const float* btq = (const float*)d_in[8];
  const float* gv  = (const float*)d_in[9];
  const float* btv = (const float*)d_in[10];
  float* out = (float*)d_out;
  float* ws  = (float*)d_ws;

  // workspace layout (f32-element offsets)
  float* G    = ws;                       // 65536
  float* XP   = ws + 65536;               // 262144
  float* XSUM = ws + 327680;              // 256
  float* RMAX = ws + 327936;              // 1024
  float* RSUM = ws + 328960;              // 1024
  float* AV   = ws + 329984;              // 1024
  float* BVa  = ws + 331008;              // 1024
  float* AQ   = ws + 332032;              // 16
  float* BQa  = ws + 332048;              // 16 (pad to 332288)
  float* CTX  = ws + 332288;              // 65536 -> ends 397824
  float* KB   = ws + 397824;              // 4194304
  float* QB   = ws + 4592128;             // 1048576
  u32*  PART  = (u32*)(ws + 397824);      // 8388608 u32 (aliases KB/QB; disjoint lifetime)
  unsigned short* XBF = (unsigned short*)(ws + 8786432);  // 16777216 bf16 (33.5 MB)
  // total ws use: (8786432 + 8388608) * 4 B = ~68.7 MB

  // zero atomically-accumulated buffers (XP, XSUM contiguous)
  hipMemsetAsync(ws + 65536, 0, (size_t)(262144 + 256) * sizeof(float), stream);

  k_cvt_g <<<256,  512, 0, stream>>>(x, XBF, XSUM, PART);
  k_gred  <<<128,  256, 0, stream>>>(PART, G);
  k_proj  <<<512,  256, 0, stream>>>(XBF, Wq, bq, Wk, bk, KB, QB);
  k_sstats<<<1024, 256, 0, stream>>>(KB, RMAX, RSUM);
  k_fin   <<<1040, 256, 0, stream>>>(G, XSUM, Wv, bv, gv, btv, Wq, bq, gq, btq,
                                     AV, BVa, AQ, BQa);
  k_xp    <<<128,  256, 0, stream>>>(XBF, KB, RMAX, XP);
  k_ctx   <<<256,  256, 0, stream>>>(XP, RSUM, Wv, bv, AV, BVa, CTX);
  k_y     <<<256,  256, 0, stream>>>(QB, CTX, AQ, BQa, out);
}

// Round 5
// 198.920 us; speedup vs baseline: 1.8437x; 1.8437x over previous
//
#include <hip/hip_runtime.h>
#include <hip/hip_bf16.h>

typedef short s16x8 __attribute__((ext_vector_type(8)));
typedef short s16x4 __attribute__((ext_vector_type(4)));
typedef float f32x4 __attribute__((ext_vector_type(4)));
typedef unsigned u32;
typedef u32 u32x2 __attribute__((ext_vector_type(2)));

#define DI __device__ __forceinline__

constexpr int BB = 16;    // batch
constexpr int CC = 256;   // in channels
constexpr int MM = 4096;  // H*W
constexpr int KD = 16;    // k
constexpr int UK = 64;    // u*k
constexpr float EPSV = 1e-5f;

DI unsigned short f2bf(float f) {
  union { float f; unsigned u; } v; v.f = f;
  unsigned r = v.u + 0x7FFFu + ((v.u >> 16) & 1u);
  return (unsigned short)(r >> 16);
}
DI float bflo(u32 v) { union { u32 u; float f; } w; w.u = v << 16; return w.f; }
DI float bfhi(u32 v) { union { u32 u; float f; } w; w.u = v & 0xFFFF0000u; return w.f; }

// ---- streaming convert x f32 -> bf16, fused per-channel xsum ----
__global__ __launch_bounds__(256) void k_cvt(const float* __restrict__ x,
    unsigned short* __restrict__ xbf, float* __restrict__ xsum) {
  int bid = blockIdx.x;                 // b*256 + c
  size_t base = (size_t)bid * MM;
  int t = threadIdx.x;
  float s = 0.f;
#pragma unroll
  for (int i = 0; i < 4; ++i) {
    size_t idx = base + (size_t)(i * 256 + t) * 4;
    float4 v = *(const float4*)(x + idx);
    s16x4 c;
    c[0] = (short)f2bf(v.x); c[1] = (short)f2bf(v.y);
    c[2] = (short)f2bf(v.z); c[3] = (short)f2bf(v.w);
    *(s16x4*)&xbf[idx] = c;
    s += v.x + v.y + v.z + v.w;
  }
#pragma unroll
  for (int o = 32; o; o >>= 1) s += __shfl_down(s, o);
  __shared__ float red[4];
  if ((t & 63) == 0) red[t >> 6] = s;
  __syncthreads();
  if (t == 0) atomicAdd(&xsum[bid & 255], red[0] + red[1] + red[2] + red[3]);
}

// ---- G-partial = X_chunk X_chunk^T (bf16 MFMA, double-buffered LDS) ----
// grid 256 = (b, mc of 256 m); 512 thr = 8 waves, wave tile 128x64
__global__ __launch_bounds__(512) void k_gxx(const unsigned short* __restrict__ xbf,
                                             u32* __restrict__ part) {
  int b = blockIdx.x >> 4, mc = blockIdx.x & 15;
  int m0 = mc * 256;
  __shared__ short lds[2][256 * 72];    // pitch 72 bf16 = 144B (16B-aligned rows)
  int t = threadIdx.x, w = t >> 6, l = t & 63;
  int wr = w >> 2, wc = w & 3;
  int lrow = l & 15, lk8 = (l >> 4) * 8;
  int srow = t >> 3, sseg = (t & 7) * 8;   // staging: 8 lanes cover one row's 128B

  const unsigned short* gsrc = xbf + ((size_t)(b * CC + srow)) * MM + m0 + sseg;

  s16x8 rg[4];
#pragma unroll
  for (int i = 0; i < 4; ++i)
    rg[i] = *(const s16x8*)(gsrc + (size_t)i * 64 * MM);
#pragma unroll
  for (int i = 0; i < 4; ++i)
    *(s16x8*)&lds[0][(srow + i * 64) * 72 + sseg] = rg[i];

  f32x4 acc[8][4];
#pragma unroll
  for (int i = 0; i < 8; ++i)
#pragma unroll
    for (int j = 0; j < 4; ++j) acc[i][j] = (f32x4)0.f;

#pragma unroll
  for (int ks = 0; ks < 4; ++ks) {
    __syncthreads();
    if (ks < 3) {   // issue next-step global loads early (overlap with MFMA below)
#pragma unroll
      for (int i = 0; i < 4; ++i)
        rg[i] = *(const s16x8*)(gsrc + (size_t)i * 64 * MM + (ks + 1) * 64);
    }
    int buf = ks & 1;
#pragma unroll
    for (int half = 0; half < 2; ++half) {
      s16x8 af[8], bf[4];
#pragma unroll
      for (int i = 0; i < 8; ++i)
        af[i] = *(const s16x8*)&lds[buf][(wr * 128 + i * 16 + lrow) * 72 + half * 32 + lk8];
#pragma unroll
      for (int j = 0; j < 4; ++j)
        bf[j] = *(const s16x8*)&lds[buf][(wc * 64 + j * 16 + lrow) * 72 + half * 32 + lk8];
#pragma unroll
      for (int i = 0; i < 8; ++i)
#pragma unroll
        for (int j = 0; j < 4; ++j)
          acc[i][j] = __builtin_amdgcn_mfma_f32_16x16x32_bf16(af[i], bf[j], acc[i][j], 0, 0, 0);
    }
    if (ks < 3) {   // write-late into the other buffer (safe: top sync separates)
#pragma unroll
      for (int i = 0; i < 4; ++i)
        *(s16x8*)&lds[buf ^ 1][(srow + i * 64) * 72 + sseg] = rg[i];
    }
  }

  // epilogue: packed bf16 partial, lane-minor flat layout (coalesced)
  size_t pb = (size_t)blockIdx.x * 32768;
#pragma unroll
  for (int i = 0; i < 8; ++i)
#pragma unroll
    for (int j = 0; j < 4; ++j) {
      int tau = (w * 8 + i) * 4 + j;
      u32x2 pk;
      pk[0] = (u32)f2bf(acc[i][j][0]) | ((u32)f2bf(acc[i][j][1]) << 16);
      pk[1] = (u32)f2bf(acc[i][j][2]) | ((u32)f2bf(acc[i][j][3]) << 16);
      *(u32x2*)&part[pb + tau * 128 + l * 2] = pk;
    }
}

// ---- reduce 256 G-partials -> G ----
__global__ __launch_bounds__(256) void k_gred(const u32* __restrict__ part,
                                              float* __restrict__ G) {
  int q = blockIdx.x * 256 + threadIdx.x;   // 0..32767
  float s0 = 0.f, s1 = 0.f;
#pragma unroll 8
  for (int p = 0; p < 256; ++p) {
    u32 v = part[(size_t)p * 32768 + q];
    s0 += bflo(v);
    s1 += bfhi(v);
  }
  int r2 = q & 1, l = (q >> 1) & 63, tau = q >> 7;
  int j = tau & 3, i = (tau >> 2) & 7, w = tau >> 5;
  int wr = w >> 2, wc = w & 3;
  int row = wr * 128 + i * 16 + (l >> 4) * 4 + r2 * 2;
  int col = wc * 64 + j * 16 + (l & 15);
  G[row * 256 + col] = s0;
  G[(row + 1) * 256 + col] = s1;
}

// ---------------- Q/K projection via bf16 MFMA (reads bf16 x) ----------------
__global__ __launch_bounds__(256) void k_proj(const unsigned short* __restrict__ xbf,
    const float* __restrict__ Wq, const float* __restrict__ bq,
    const float* __restrict__ Wk, const float* __restrict__ bk,
    float* __restrict__ Kb, float* __restrict__ Qb) {
  int b = blockIdx.x >> 5, mc = blockIdx.x & 31;   // 16 b * 32 m-chunks
  int gm0 = mc * 128;
  __shared__ short wlds[80 * 264];                 // W bf16, pitch 264
  __shared__ u32 xt[128 * 17];                     // x^T tile: [m][c-pair], pitch 17
  int t = threadIdx.x;
  int w = t >> 6, l = t & 63;
  int lrow = l & 15, lk = l >> 4;                  // lk in 0..3

#pragma unroll 4
  for (int o = 0; o < 80; ++o) {
    float v = (o < 64) ? Wk[o * CC + t] : Wq[(o - 64) * CC + t];
    wlds[o * 264 + t] = (short)f2bf(v);
  }

  f32x4 acc[5][2];
#pragma unroll
  for (int i = 0; i < 5; ++i) { acc[i][0] = (f32x4)0.f; acc[i][1] = (f32x4)0.f; }

  int c2 = t >> 4;          // c-pair column 0..15
  int mq = t & 15;          // m quad index

  for (int ks = 0; ks < 8; ++ks) {
    int c0 = ks * 32;
    __syncthreads();
#pragma unroll
    for (int mb = 0; mb < 128; mb += 64) {
      int m = mb + mq * 4;
      const unsigned short* p0 = xbf + ((size_t)(b * CC + c0 + 2 * c2)) * MM + gm0 + m;
      s16x4 v0 = *(const s16x4*)p0;
      s16x4 v1 = *(const s16x4*)(p0 + MM);
      xt[(m + 0) * 17 + c2] = (u32)(unsigned short)v0[0] | ((u32)(unsigned short)v1[0] << 16);
      xt[(m + 1) * 17 + c2] = (u32)(unsigned short)v0[1] | ((u32)(unsigned short)v1[1] << 16);
      xt[(m + 2) * 17 + c2] = (u32)(unsigned short)v0[2] | ((u32)(unsigned short)v1[2] << 16);
      xt[(m + 3) * 17 + c2] = (u32)(unsigned short)v0[3] | ((u32)(unsigned short)v1[3] << 16);
    }
    __syncthreads();
    union { s16x8 v; u32 wd[4]; } bfr[2];
#pragma unroll
    for (int j = 0; j < 2; ++j) {
      int ml = w * 32 + j * 16 + lrow;
#pragma unroll
      for (int i = 0; i < 4; ++i) bfr[j].wd[i] = xt[ml * 17 + lk * 4 + i];
    }
#pragma unroll
    for (int ot = 0; ot < 5; ++ot) {
      s16x8 af = *(const s16x8*)&wlds[(ot * 16 + lrow) * 264 + c0 + lk * 8];
      acc[ot][0] = __builtin_amdgcn_mfma_f32_16x16x32_bf16(af, bfr[0].v, acc[ot][0], 0, 0, 0);
      acc[ot][1] = __builtin_amdgcn_mfma_f32_16x16x32_bf16(af, bfr[1].v, acc[ot][1], 0, 0, 0);
    }
  }

#pragma unroll
  for (int ot = 0; ot < 5; ++ot)
#pragma unroll
    for (int j = 0; j < 2; ++j)
#pragma unroll
      for (int r = 0; r < 4; ++r) {
        int o = ot * 16 + lk * 4 + r;
        int m = gm0 + w * 32 + j * 16 + lrow;
        float val = acc[ot][j][r];
        if (o < 64) Kb[((size_t)(b * UK + o)) * MM + m] = val + bk[o];
        else        Qb[((size_t)(b * KD + o - 64)) * MM + m] = val + bq[o - 64];
      }
}

// ---------------- softmax row stats over K ----------------
__global__ __launch_bounds__(256) void k_sstats(const float* __restrict__ Kb,
    float* __restrict__ rmax, float* __restrict__ rsum) {
  int r = blockIdx.x;                    // 0..1023
  int t = threadIdx.x;
  const float4* p = (const float4*)(Kb + (size_t)r * MM);
  float4 v[4];
  float mx = -3.4e38f;
#pragma unroll
  for (int i = 0; i < 4; ++i) {
    v[i] = p[i * 256 + t];
    mx = fmaxf(mx, fmaxf(fmaxf(v[i].x, v[i].y), fmaxf(v[i].z, v[i].w)));
  }
#pragma unroll
  for (int o = 32; o; o >>= 1) mx = fmaxf(mx, __shfl_xor(mx, o));
  __shared__ float red[4];
  int w = t >> 6;
  if ((t & 63) == 0) red[w] = mx;
  __syncthreads();
  mx = fmaxf(fmaxf(red[0], red[1]), fmaxf(red[2], red[3]));
  float s = 0.f;
#pragma unroll
  for (int i = 0; i < 4; ++i)
    s += __expf(v[i].x - mx) + __expf(v[i].y - mx) +
         __expf(v[i].z - mx) + __expf(v[i].w - mx);
#pragma unroll
  for (int o = 32; o; o >>= 1) s += __shfl_xor(s, o);
  __syncthreads();
  if ((t & 63) == 0) red[w] = s;
  __syncthreads();
  if (t == 0) {
    rmax[r] = mx;
    rsum[r] = red[0] + red[1] + red[2] + red[3];
  }
}

// ---------------- BN affine params from G, xsum ----------------
__global__ __launch_bounds__(256) void k_fin(const float* __restrict__ G,
    const float* __restrict__ xsum,
    const float* __restrict__ Wv, const float* __restrict__ bv,
    const float* __restrict__ gv, const float* __restrict__ btv,
    const float* __restrict__ Wq, const float* __restrict__ bq,
    const float* __restrict__ gq, const float* __restrict__ btq,
    float* __restrict__ AV, float* __restrict__ BVa,
    float* __restrict__ AQ, float* __restrict__ BQa) {
  int o = blockIdx.x;                    // 0..1039: 0..1023 V-ch, 1024.. Q-ch
  int t = threadIdx.x;
  const float* w; float bias, gamma, beta; float* pa; float* pb;
  if (o < 1024) {
    w = Wv + (size_t)o * CC; bias = bv[o]; gamma = gv[o]; beta = btv[o];
    pa = AV + o; pb = BVa + o;
  } else {
    int oi = o - 1024;
    w = Wq + (size_t)oi * CC; bias = bq[oi]; gamma = gq[oi]; beta = btq[oi];
    pa = AQ + oi; pb = BQa + oi;
  }
  __shared__ float lw[256];
  lw[t] = w[t];
  __syncthreads();
  const float* g = G + (size_t)t * CC;
  float tv = 0.f;
#pragma unroll 8
  for (int c = 0; c < CC; c += 4) {
    float4 g4 = *(const float4*)(g + c);
    tv += g4.x * lw[c] + g4.y * lw[c + 1] + g4.z * lw[c + 2] + g4.w * lw[c + 3];
  }
  float qf = tv * lw[t];
  float sx = lw[t] * xsum[t];
#pragma unroll
  for (int od = 32; od; od >>= 1) { qf += __shfl_xor(qf, od); sx += __shfl_xor(sx, od); }
  __shared__ float r1[4], r2[4];
  int wv = t >> 6;
  if ((t & 63) == 0) { r1[wv] = qf; r2[wv] = sx; }
  __syncthreads();
  if (t == 0) {
    qf = r1[0] + r1[1] + r1[2] + r1[3];
    sx = r2[0] + r2[1] + r2[2] + r2[3];
    const float invN = 1.f / 65536.f;
    float mean = sx * invN + bias;
    float e2 = qf * invN + 2.f * bias * sx * invN + bias * bias;
    float var = e2 - mean * mean;
    float a = gamma * rsqrtf(var + EPSV);
    *pa = a;
    *pb = beta - mean * a;
  }
}

// ---------------- xp[b,j,c] = sum_m exp(K[b,j,m]-rmax) * x[b,c,m] ----------------
__global__ __launch_bounds__(256) void k_xp(const unsigned short* __restrict__ xbf,
    const float* __restrict__ Kb, const float* __restrict__ rmax,
    float* __restrict__ XP) {
  int b = blockIdx.x >> 4, kc = blockIdx.x & 15;
  int kbase = kc * 256;
  __shared__ short la[64][40];
  __shared__ short lb[256][40];
  int t = threadIdx.x, w = t >> 6, l = t & 63;
  int lrow = l & 15, lk = (l >> 4) * 8;

  f32x4 acc[4][4];
#pragma unroll
  for (int i = 0; i < 4; ++i)
#pragma unroll
    for (int j = 0; j < 4; ++j) acc[i][j] = (f32x4)0.f;

  for (int ks = 0; ks < 8; ++ks) {
    int k0 = kbase + ks * 32;
    __syncthreads();
    {   // stage A: exp(K - rmax), 64 rows x 32 (K is f32)
      int r = t >> 2, sg = (t & 3) * 8;
      const float4* src = (const float4*)(Kb + ((size_t)(b * UK + r)) * MM + k0 + sg);
      float rm = rmax[b * UK + r];
      s16x8 wv;
#pragma unroll
      for (int i = 0; i < 2; ++i) {
        float4 v = src[i];
        wv[i * 4 + 0] = (short)f2bf(__expf(v.x - rm));
        wv[i * 4 + 1] = (short)f2bf(__expf(v.y - rm));
        wv[i * 4 + 2] = (short)f2bf(__expf(v.z - rm));
        wv[i * 4 + 3] = (short)f2bf(__expf(v.w - rm));
      }
      *(s16x8*)&la[r][sg] = wv;
    }
#pragma unroll
    for (int i = 0; i < 4; ++i) {   // stage B: bf16 x, 256 rows x 32
      int r = i * 64 + (t >> 2), sg = (t & 3) * 8;
      s16x8 v = *(const s16x8*)&xbf[((size_t)(b * CC + r)) * MM + k0 + sg];
      *(s16x8*)&lb[r][sg] = v;
    }
    __syncthreads();
    s16x8 af[4], bfr[4];
#pragma unroll
    for (int i = 0; i < 4; ++i) af[i] = *(const s16x8*)&la[i * 16 + lrow][lk];
#pragma unroll
    for (int j = 0; j < 4; ++j) bfr[j] = *(const s16x8*)&lb[w * 64 + j * 16 + lrow][lk];
#pragma unroll
    for (int i = 0; i < 4; ++i)
#pragma unroll
      for (int j = 0; j < 4; ++j)
        acc[i][j] = __builtin_amdgcn_mfma_f32_16x16x32_bf16(af[i], bfr[j], acc[i][j], 0, 0, 0);
  }
#pragma unroll
  for (int i = 0; i < 4; ++i)
#pragma unroll
    for (int j = 0; j < 4; ++j)
#pragma unroll
      for (int r = 0; r < 4; ++r) {
        int row = i * 16 + (l >> 4) * 4 + r;       // j index 0..63
        int col = w * 64 + j * 16 + lrow;          // c index 0..255
        atomicAdd(&XP[((size_t)b * UK + row) * CC + col], acc[i][j][r]);
      }
}

// ---------------- ctx[b,kk,vv] = sum_u aV*(Wv . xp_n + bv) + bVa ----------------
__global__ __launch_bounds__(256) void k_ctx(const float* __restrict__ XP,
    const float* __restrict__ rsum,
    const float* __restrict__ Wv, const float* __restrict__ bv,
    const float* __restrict__ AV, const float* __restrict__ BVa,
    float* __restrict__ CTX) {
  int b = blockIdx.x >> 4, kk = blockIdx.x & 15;
  __shared__ float lxp[4][256];
  int t = threadIdx.x;
#pragma unroll
  for (int u = 0; u < 4; ++u) {
    int row = b * UK + u * KD + kk;
    lxp[u][t] = XP[(size_t)row * CC + t] / rsum[row];
  }
  __syncthreads();
  float acc = 0.f;
#pragma unroll
  for (int u = 0; u < 4; ++u) {
    int ch = u * 256 + t;
    const float4* wv4 = (const float4*)(Wv + (size_t)ch * CC);
    float dot = 0.f;
#pragma unroll 8
    for (int c4 = 0; c4 < 64; ++c4) {
      float4 wv = wv4[c4];
      dot += wv.x * lxp[u][c4 * 4 + 0] + wv.y * lxp[u][c4 * 4 + 1] +
             wv.z * lxp[u][c4 * 4 + 2] + wv.w * lxp[u][c4 * 4 + 3];
    }
    acc += AV[ch] * (dot + bv[ch]) + BVa[ch];
  }
  CTX[((size_t)b * KD + kk) * 256 + t] = acc;
}

// ---------------- y[b,vv,m] = sum_kk (aQ*Q+bQ)[kk,m] * ctx[kk,vv] ----------------
__global__ __launch_bounds__(256) void k_y(const float* __restrict__ Qb,
    const float* __restrict__ CTX,
    const float* __restrict__ AQ, const float* __restrict__ BQa,
    float* __restrict__ y) {
  int b = blockIdx.x >> 4, nc = blockIdx.x & 15;
  int m = nc * 256 + threadIdx.x;
  float qn[16];
#pragma unroll
  for (int kk = 0; kk < 16; ++kk)
    qn[kk] = AQ[kk] * Qb[((size_t)b * KD + kk) * MM + m] + BQa[kk];
  const float* cb = CTX + (size_t)b * KD * 256;
  float* yo = y + (size_t)b * 256 * MM + m;
#pragma unroll 4
  for (int vv = 0; vv < 256; ++vv) {
    float acc = 0.f;
#pragma unroll
    for (int kk = 0; kk < 16; ++kk)
      acc = fmaf(qn[kk], cb[kk * 256 + vv], acc);   // uniform -> scalar loads
    yo[(size_t)vv * MM] = acc;
  }
}

extern "C" void kernel_launch(void* const* d_in, const int* in_sizes, int n_in,
                              void* d_out, int out_size, void* d_ws, size_t ws_size,
                              hipStream_t stream) {
  const float* x   = (const float*)d_in[0];
  const float* Wq  = (const float*)d_in[1];
  const float* bq  = (const float*)d_in[2];
  const float* Wk  = (const float*)d_in[3];
  const float* bk  = (const float*)d_in[4];
  const float* Wv  = (const float*)d_in[5];
  const float* bv  = (const float*)d_in[6];
  const float* gq  = (const float*)d_in[7];
  const float* btq = (const float*)d_in[8];
  const float* gv  = (const float*)d_in[9];
  const float* btv = (const float*)d_in[10];
  float* out = (float*)d_out;
  float* ws  = (float*)d_ws;

  // workspace layout (f32-element offsets)
  float* G    = ws;                       // 65536
  float* XP   = ws + 65536;               // 262144
  float* XSUM = ws + 327680;              // 256
  float* RMAX = ws + 327936;              // 1024
  float* RSUM = ws + 328960;              // 1024
  float* AV   = ws + 329984;              // 1024
  float* BVa  = ws + 331008;              // 1024
  float* AQ   = ws + 332032;              // 16
  float* BQa  = ws + 332048;              // 16 (pad to 332288)
  float* CTX  = ws + 332288;              // 65536 -> ends 397824
  float* KB   = ws + 397824;              // 4194304
  float* QB   = ws + 4592128;             // 1048576
  u32*  PART  = (u32*)(ws + 397824);      // 8388608 u32 (aliases KB/QB; disjoint lifetime)
  unsigned short* XBF = (unsigned short*)(ws + 8786432);  // 16777216 bf16 (33.5 MB)
  // total ws use: ~68.7 MB

  // zero atomically-accumulated buffers (XP, XSUM contiguous)
  hipMemsetAsync(ws + 65536, 0, (size_t)(262144 + 256) * sizeof(float), stream);

  k_cvt   <<<4096, 256, 0, stream>>>(x, XBF, XSUM);
  k_gxx   <<<256,  512, 0, stream>>>(XBF, PART);
  k_gred  <<<128,  256, 0, stream>>>(PART, G);
  k_proj  <<<512,  256, 0, stream>>>(XBF, Wq, bq, Wk, bk, KB, QB);
  k_sstats<<<1024, 256, 0, stream>>>(KB, RMAX, RSUM);
  k_fin   <<<1040, 256, 0, stream>>>(G, XSUM, Wv, bv, gv, btv, Wq, bq, gq, btq,
                                     AV, BVa, AQ, BQa);
  k_xp    <<<256,  256, 0, stream>>>(XBF, KB, RMAX, XP);
  k_ctx   <<<256,  256, 0, stream>>>(XP, RSUM, Wv, bv, AV, BVa, CTX);
  k_y     <<<256,  256, 0, stream>>>(QB, CTX, AQ, BQa, out);
}

// Round 6
// 187.179 us; speedup vs baseline: 1.9593x; 1.0627x over previous
//
#include <hip/hip_runtime.h>
#include <hip/hip_bf16.h>

typedef short s16x8 __attribute__((ext_vector_type(8)));
typedef short s16x4 __attribute__((ext_vector_type(4)));
typedef float f32x4 __attribute__((ext_vector_type(4)));
typedef unsigned u32;
typedef u32 u32x2 __attribute__((ext_vector_type(2)));

#define DI __device__ __forceinline__

constexpr int BB = 16;    // batch
constexpr int CC = 256;   // in channels
constexpr int MM = 4096;  // H*W
constexpr int KD = 16;    // k
constexpr int UK = 64;    // u*k
constexpr float EPSV = 1e-5f;

DI unsigned short f2bf(float f) {
  union { float f; unsigned u; } v; v.f = f;
  unsigned r = v.u + 0x7FFFu + ((v.u >> 16) & 1u);
  return (unsigned short)(r >> 16);
}
DI float bflo(u32 v) { union { u32 u; float f; } w; w.u = v << 16; return w.f; }
DI float bfhi(u32 v) { union { u32 u; float f; } w; w.u = v & 0xFFFF0000u; return w.f; }

// ---- streaming convert x f32 -> bf16, per-(b,c) partial sum (no atomics) ----
__global__ __launch_bounds__(256) void k_cvt(const float* __restrict__ x,
    unsigned short* __restrict__ xbf, float* __restrict__ xsump) {
  int bid = blockIdx.x;                 // b*256 + c
  size_t base = (size_t)bid * MM;
  int t = threadIdx.x;
  float s = 0.f;
#pragma unroll
  for (int i = 0; i < 4; ++i) {
    size_t idx = base + (size_t)(i * 256 + t) * 4;
    float4 v = *(const float4*)(x + idx);
    s16x4 c;
    c[0] = (short)f2bf(v.x); c[1] = (short)f2bf(v.y);
    c[2] = (short)f2bf(v.z); c[3] = (short)f2bf(v.w);
    *(s16x4*)&xbf[idx] = c;
    s += v.x + v.y + v.z + v.w;
  }
#pragma unroll
  for (int o = 32; o; o >>= 1) s += __shfl_down(s, o);
  __shared__ float red[4];
  if ((t & 63) == 0) red[t >> 6] = s;
  __syncthreads();
  if (t == 0) xsump[bid] = red[0] + red[1] + red[2] + red[3];
}

// ---- G-partial = X_chunk X_chunk^T (bf16 MFMA, double-buffered LDS) ----
// grid 256 = (b, mc of 256 m); 512 thr = 8 waves, wave tile 128x64
__global__ __launch_bounds__(512) void k_gxx(const unsigned short* __restrict__ xbf,
                                             u32* __restrict__ part) {
  int b = blockIdx.x >> 4, mc = blockIdx.x & 15;
  int m0 = mc * 256;
  __shared__ short lds[2][256 * 72];    // pitch 72 bf16 = 144B (16B-aligned rows)
  int t = threadIdx.x, w = t >> 6, l = t & 63;
  int wr = w >> 2, wc = w & 3;
  int lrow = l & 15, lk8 = (l >> 4) * 8;
  int srow = t >> 3, sseg = (t & 7) * 8;   // staging: 8 lanes cover one row's 128B

  const unsigned short* gsrc = xbf + ((size_t)(b * CC + srow)) * MM + m0 + sseg;

  s16x8 rg[4];
#pragma unroll
  for (int i = 0; i < 4; ++i)
    rg[i] = *(const s16x8*)(gsrc + (size_t)i * 64 * MM);
#pragma unroll
  for (int i = 0; i < 4; ++i)
    *(s16x8*)&lds[0][(srow + i * 64) * 72 + sseg] = rg[i];

  f32x4 acc[8][4];
#pragma unroll
  for (int i = 0; i < 8; ++i)
#pragma unroll
    for (int j = 0; j < 4; ++j) acc[i][j] = (f32x4)0.f;

#pragma unroll
  for (int ks = 0; ks < 4; ++ks) {
    __syncthreads();
    if (ks < 3) {   // issue next-step global loads early (overlap with MFMA below)
#pragma unroll
      for (int i = 0; i < 4; ++i)
        rg[i] = *(const s16x8*)(gsrc + (size_t)i * 64 * MM + (ks + 1) * 64);
    }
    int buf = ks & 1;
#pragma unroll
    for (int half = 0; half < 2; ++half) {
      s16x8 af[8], bf[4];
#pragma unroll
      for (int i = 0; i < 8; ++i)
        af[i] = *(const s16x8*)&lds[buf][(wr * 128 + i * 16 + lrow) * 72 + half * 32 + lk8];
#pragma unroll
      for (int j = 0; j < 4; ++j)
        bf[j] = *(const s16x8*)&lds[buf][(wc * 64 + j * 16 + lrow) * 72 + half * 32 + lk8];
#pragma unroll
      for (int i = 0; i < 8; ++i)
#pragma unroll
        for (int j = 0; j < 4; ++j)
          acc[i][j] = __builtin_amdgcn_mfma_f32_16x16x32_bf16(af[i], bf[j], acc[i][j], 0, 0, 0);
    }
    if (ks < 3) {   // write-late into the other buffer (safe: top sync separates)
#pragma unroll
      for (int i = 0; i < 4; ++i)
        *(s16x8*)&lds[buf ^ 1][(srow + i * 64) * 72 + sseg] = rg[i];
    }
  }

  // epilogue: packed bf16 partial, lane-minor flat layout (coalesced)
  size_t pb = (size_t)blockIdx.x * 32768;
#pragma unroll
  for (int i = 0; i < 8; ++i)
#pragma unroll
    for (int j = 0; j < 4; ++j) {
      int tau = (w * 8 + i) * 4 + j;
      u32x2 pk;
      pk[0] = (u32)f2bf(acc[i][j][0]) | ((u32)f2bf(acc[i][j][1]) << 16);
      pk[1] = (u32)f2bf(acc[i][j][2]) | ((u32)f2bf(acc[i][j][3]) << 16);
      *(u32x2*)&part[pb + tau * 128 + l * 2] = pk;
    }
}

// ---- reduce 256 G-partials -> G ----
__global__ __launch_bounds__(256) void k_gred(const u32* __restrict__ part,
                                              float* __restrict__ G) {
  int q = blockIdx.x * 256 + threadIdx.x;   // 0..32767
  float s0 = 0.f, s1 = 0.f;
#pragma unroll 8
  for (int p = 0; p < 256; ++p) {
    u32 v = part[(size_t)p * 32768 + q];
    s0 += bflo(v);
    s1 += bfhi(v);
  }
  int r2 = q & 1, l = (q >> 1) & 63, tau = q >> 7;
  int j = tau & 3, i = (tau >> 2) & 7, w = tau >> 5;
  int wr = w >> 2, wc = w & 3;
  int row = wr * 128 + i * 16 + (l >> 4) * 4 + r2 * 2;
  int col = wc * 64 + j * 16 + (l & 15);
  G[row * 256 + col] = s0;
  G[(row + 1) * 256 + col] = s1;
}

// ---------------- Q/K projection via bf16 MFMA (reads bf16 x) ----------------
__global__ __launch_bounds__(256) void k_proj(const unsigned short* __restrict__ xbf,
    const float* __restrict__ Wq, const float* __restrict__ bq,
    const float* __restrict__ Wk, const float* __restrict__ bk,
    float* __restrict__ Kb, float* __restrict__ Qb) {
  int b = blockIdx.x >> 5, mc = blockIdx.x & 31;   // 16 b * 32 m-chunks
  int gm0 = mc * 128;
  __shared__ short wlds[80 * 264];                 // W bf16, pitch 264
  __shared__ u32 xt[128 * 17];                     // x^T tile: [m][c-pair], pitch 17
  int t = threadIdx.x;
  int w = t >> 6, l = t & 63;
  int lrow = l & 15, lk = l >> 4;                  // lk in 0..3

#pragma unroll 4
  for (int o = 0; o < 80; ++o) {
    float v = (o < 64) ? Wk[o * CC + t] : Wq[(o - 64) * CC + t];
    wlds[o * 264 + t] = (short)f2bf(v);
  }

  f32x4 acc[5][2];
#pragma unroll
  for (int i = 0; i < 5; ++i) { acc[i][0] = (f32x4)0.f; acc[i][1] = (f32x4)0.f; }

  int c2 = t >> 4;          // c-pair column 0..15
  int mq = t & 15;          // m quad index

  for (int ks = 0; ks < 8; ++ks) {
    int c0 = ks * 32;
    __syncthreads();
#pragma unroll
    for (int mb = 0; mb < 128; mb += 64) {
      int m = mb + mq * 4;
      const unsigned short* p0 = xbf + ((size_t)(b * CC + c0 + 2 * c2)) * MM + gm0 + m;
      s16x4 v0 = *(const s16x4*)p0;
      s16x4 v1 = *(const s16x4*)(p0 + MM);
      xt[(m + 0) * 17 + c2] = (u32)(unsigned short)v0[0] | ((u32)(unsigned short)v1[0] << 16);
      xt[(m + 1) * 17 + c2] = (u32)(unsigned short)v0[1] | ((u32)(unsigned short)v1[1] << 16);
      xt[(m + 2) * 17 + c2] = (u32)(unsigned short)v0[2] | ((u32)(unsigned short)v1[2] << 16);
      xt[(m + 3) * 17 + c2] = (u32)(unsigned short)v0[3] | ((u32)(unsigned short)v1[3] << 16);
    }
    __syncthreads();
    union { s16x8 v; u32 wd[4]; } bfr[2];
#pragma unroll
    for (int j = 0; j < 2; ++j) {
      int ml = w * 32 + j * 16 + lrow;
#pragma unroll
      for (int i = 0; i < 4; ++i) bfr[j].wd[i] = xt[ml * 17 + lk * 4 + i];
    }
#pragma unroll
    for (int ot = 0; ot < 5; ++ot) {
      s16x8 af = *(const s16x8*)&wlds[(ot * 16 + lrow) * 264 + c0 + lk * 8];
      acc[ot][0] = __builtin_amdgcn_mfma_f32_16x16x32_bf16(af, bfr[0].v, acc[ot][0], 0, 0, 0);
      acc[ot][1] = __builtin_amdgcn_mfma_f32_16x16x32_bf16(af, bfr[1].v, acc[ot][1], 0, 0, 0);
    }
  }

#pragma unroll
  for (int ot = 0; ot < 5; ++ot)
#pragma unroll
    for (int j = 0; j < 2; ++j)
#pragma unroll
      for (int r = 0; r < 4; ++r) {
        int o = ot * 16 + lk * 4 + r;
        int m = gm0 + w * 32 + j * 16 + lrow;
        float val = acc[ot][j][r];
        if (o < 64) Kb[((size_t)(b * UK + o)) * MM + m] = val + bk[o];
        else        Qb[((size_t)(b * KD + o - 64)) * MM + m] = val + bq[o - 64];
      }
}

// ---------------- softmax row stats over K ----------------
__global__ __launch_bounds__(256) void k_sstats(const float* __restrict__ Kb,
    float* __restrict__ rmax, float* __restrict__ rsum) {
  int r = blockIdx.x;                    // 0..1023
  int t = threadIdx.x;
  const float4* p = (const float4*)(Kb + (size_t)r * MM);
  float4 v[4];
  float mx = -3.4e38f;
#pragma unroll
  for (int i = 0; i < 4; ++i) {
    v[i] = p[i * 256 + t];
    mx = fmaxf(mx, fmaxf(fmaxf(v[i].x, v[i].y), fmaxf(v[i].z, v[i].w)));
  }
#pragma unroll
  for (int o = 32; o; o >>= 1) mx = fmaxf(mx, __shfl_xor(mx, o));
  __shared__ float red[4];
  int w = t >> 6;
  if ((t & 63) == 0) red[w] = mx;
  __syncthreads();
  mx = fmaxf(fmaxf(red[0], red[1]), fmaxf(red[2], red[3]));
  float s = 0.f;
#pragma unroll
  for (int i = 0; i < 4; ++i)
    s += __expf(v[i].x - mx) + __expf(v[i].y - mx) +
         __expf(v[i].z - mx) + __expf(v[i].w - mx);
#pragma unroll
  for (int o = 32; o; o >>= 1) s += __shfl_xor(s, o);
  __syncthreads();
  if ((t & 63) == 0) red[w] = s;
  __syncthreads();
  if (t == 0) {
    rmax[r] = mx;
    rsum[r] = red[0] + red[1] + red[2] + red[3];
  }
}

// ---------------- BN affine params from G, xsum-partials ----------------
__global__ __launch_bounds__(256) void k_fin(const float* __restrict__ G,
    const float* __restrict__ xsump,
    const float* __restrict__ Wv, const float* __restrict__ bv,
    const float* __restrict__ gv, const float* __restrict__ btv,
    const float* __restrict__ Wq, const float* __restrict__ bq,
    const float* __restrict__ gq, const float* __restrict__ btq,
    float* __restrict__ AV, float* __restrict__ BVa,
    float* __restrict__ AQ, float* __restrict__ BQa) {
  int o = blockIdx.x;                    // 0..1039: 0..1023 V-ch, 1024.. Q-ch
  int t = threadIdx.x;
  const float* w; float bias, gamma, beta; float* pa; float* pb;
  if (o < 1024) {
    w = Wv + (size_t)o * CC; bias = bv[o]; gamma = gv[o]; beta = btv[o];
    pa = AV + o; pb = BVa + o;
  } else {
    int oi = o - 1024;
    w = Wq + (size_t)oi * CC; bias = bq[oi]; gamma = gq[oi]; beta = btq[oi];
    pa = AQ + oi; pb = BQa + oi;
  }
  __shared__ float lw[256];
  lw[t] = w[t];
  __syncthreads();
  float xs = 0.f;
#pragma unroll
  for (int bb = 0; bb < 16; ++bb) xs += xsump[bb * 256 + t];
  const float* g = G + (size_t)t * CC;
  float tv = 0.f;
#pragma unroll 8
  for (int c = 0; c < CC; c += 4) {
    float4 g4 = *(const float4*)(g + c);
    tv += g4.x * lw[c] + g4.y * lw[c + 1] + g4.z * lw[c + 2] + g4.w * lw[c + 3];
  }
  float qf = tv * lw[t];
  float sx = lw[t] * xs;
#pragma unroll
  for (int od = 32; od; od >>= 1) { qf += __shfl_xor(qf, od); sx += __shfl_xor(sx, od); }
  __shared__ float r1[4], r2[4];
  int wv = t >> 6;
  if ((t & 63) == 0) { r1[wv] = qf; r2[wv] = sx; }
  __syncthreads();
  if (t == 0) {
    qf = r1[0] + r1[1] + r1[2] + r1[3];
    sx = r2[0] + r2[1] + r2[2] + r2[3];
    const float invN = 1.f / 65536.f;
    float mean = sx * invN + bias;
    float e2 = qf * invN + 2.f * bias * sx * invN + bias * bias;
    float var = e2 - mean * mean;
    float a = gamma * rsqrtf(var + EPSV);
    *pa = a;
    *pb = beta - mean * a;
  }
}

// ---- xp-partial[b,kc,j,c] = sum_{m in kc} exp(K-rmax) * x  (no atomics) ----
__global__ __launch_bounds__(256) void k_xp(const unsigned short* __restrict__ xbf,
    const float* __restrict__ Kb, const float* __restrict__ rmax,
    float* __restrict__ xpp) {
  int b = blockIdx.x >> 4, kc = blockIdx.x & 15;
  int kbase = kc * 256;
  __shared__ short la[64][40];
  __shared__ short lb[256][40];
  int t = threadIdx.x, w = t >> 6, l = t & 63;
  int lrow = l & 15, lk = (l >> 4) * 8;

  f32x4 acc[4][4];
#pragma unroll
  for (int i = 0; i < 4; ++i)
#pragma unroll
    for (int j = 0; j < 4; ++j) acc[i][j] = (f32x4)0.f;

  for (int ks = 0; ks < 8; ++ks) {
    int k0 = kbase + ks * 32;
    __syncthreads();
    {   // stage A: exp(K - rmax), 64 rows x 32 (K is f32)
      int r = t >> 2, sg = (t & 3) * 8;
      const float4* src = (const float4*)(Kb + ((size_t)(b * UK + r)) * MM + k0 + sg);
      float rm = rmax[b * UK + r];
      s16x8 wv;
#pragma unroll
      for (int i = 0; i < 2; ++i) {
        float4 v = src[i];
        wv[i * 4 + 0] = (short)f2bf(__expf(v.x - rm));
        wv[i * 4 + 1] = (short)f2bf(__expf(v.y - rm));
        wv[i * 4 + 2] = (short)f2bf(__expf(v.z - rm));
        wv[i * 4 + 3] = (short)f2bf(__expf(v.w - rm));
      }
      *(s16x8*)&la[r][sg] = wv;
    }
#pragma unroll
    for (int i = 0; i < 4; ++i) {   // stage B: bf16 x, 256 rows x 32
      int r = i * 64 + (t >> 2), sg = (t & 3) * 8;
      s16x8 v = *(const s16x8*)&xbf[((size_t)(b * CC + r)) * MM + k0 + sg];
      *(s16x8*)&lb[r][sg] = v;
    }
    __syncthreads();
    s16x8 af[4], bfr[4];
#pragma unroll
    for (int i = 0; i < 4; ++i) af[i] = *(const s16x8*)&la[i * 16 + lrow][lk];
#pragma unroll
    for (int j = 0; j < 4; ++j) bfr[j] = *(const s16x8*)&lb[w * 64 + j * 16 + lrow][lk];
#pragma unroll
    for (int i = 0; i < 4; ++i)
#pragma unroll
      for (int j = 0; j < 4; ++j)
        acc[i][j] = __builtin_amdgcn_mfma_f32_16x16x32_bf16(af[i], bfr[j], acc[i][j], 0, 0, 0);
  }
  float* dst = xpp + (size_t)blockIdx.x * UK * CC;
#pragma unroll
  for (int i = 0; i < 4; ++i)
#pragma unroll
    for (int j = 0; j < 4; ++j)
#pragma unroll
      for (int r = 0; r < 4; ++r) {
        int row = i * 16 + (l >> 4) * 4 + r;       // j index 0..63
        int col = w * 64 + j * 16 + lrow;          // c index 0..255
        dst[row * 256 + col] = acc[i][j][r];
      }
}

// ---- ctx[b,kk,vv] = sum_u aV*(Wv . xp_n + bv) + bVa  (reduces kc-partials) ----
__global__ __launch_bounds__(256) void k_ctx(const float* __restrict__ xpp,
    const float* __restrict__ rsum,
    const float* __restrict__ Wv, const float* __restrict__ bv,
    const float* __restrict__ AV, const float* __restrict__ BVa,
    float* __restrict__ CTX) {
  int b = blockIdx.x >> 4, kk = blockIdx.x & 15;
  __shared__ float lxp[4][256];
  int t = threadIdx.x;
#pragma unroll
  for (int u = 0; u < 4; ++u) {
    int row = u * KD + kk;
    float s = 0.f;
#pragma unroll
    for (int kc = 0; kc < 16; ++kc)
      s += xpp[((size_t)(b * 16 + kc) * UK + row) * CC + t];
    lxp[u][t] = s / rsum[b * UK + row];
  }
  __syncthreads();
  float acc = 0.f;
#pragma unroll
  for (int u = 0; u < 4; ++u) {
    int ch = u * 256 + t;
    const float4* wv4 = (const float4*)(Wv + (size_t)ch * CC);
    float dot = 0.f;
#pragma unroll 8
    for (int c4 = 0; c4 < 64; ++c4) {
      float4 wv = wv4[c4];
      dot += wv.x * lxp[u][c4 * 4 + 0] + wv.y * lxp[u][c4 * 4 + 1] +
             wv.z * lxp[u][c4 * 4 + 2] + wv.w * lxp[u][c4 * 4 + 3];
    }
    acc += AV[ch] * (dot + bv[ch]) + BVa[ch];
  }
  CTX[((size_t)b * KD + kk) * 256 + t] = acc;
}

// ---------------- y[b,vv,m] = sum_kk (aQ*Q+bQ)[kk,m] * ctx[kk,vv] ----------------
__global__ __launch_bounds__(256) void k_y(const float* __restrict__ Qb,
    const float* __restrict__ CTX,
    const float* __restrict__ AQ, const float* __restrict__ BQa,
    float* __restrict__ y) {
  int b = blockIdx.x >> 4, nc = blockIdx.x & 15;
  int m = nc * 256 + threadIdx.x;
  float qn[16];
#pragma unroll
  for (int kk = 0; kk < 16; ++kk)
    qn[kk] = AQ[kk] * Qb[((size_t)b * KD + kk) * MM + m] + BQa[kk];
  const float* cb = CTX + (size_t)b * KD * 256;
  float* yo = y + (size_t)b * 256 * MM + m;
#pragma unroll 4
  for (int vv = 0; vv < 256; ++vv) {
    float acc = 0.f;
#pragma unroll
    for (int kk = 0; kk < 16; ++kk)
      acc = fmaf(qn[kk], cb[kk * 256 + vv], acc);   // uniform -> scalar loads
    yo[(size_t)vv * MM] = acc;
  }
}

extern "C" void kernel_launch(void* const* d_in, const int* in_sizes, int n_in,
                              void* d_out, int out_size, void* d_ws, size_t ws_size,
                              hipStream_t stream) {
  const float* x   = (const float*)d_in[0];
  const float* Wq  = (const float*)d_in[1];
  const float* bq  = (const float*)d_in[2];
  const float* Wk  = (const float*)d_in[3];
  const float* bk  = (const float*)d_in[4];
  const float* Wv  = (const float*)d_in[5];
  const float* bv  = (const float*)d_in[6];
  const float* gq  = (const float*)d_in[7];
  const float* btq = (const float*)d_in[8];
  const float* gv  = (const float*)d_in[9];
  const float* btv = (const float*)d_in[10];
  float* out = (float*)d_out;
  float* ws  = (float*)d_ws;

  // workspace layout (f32-element offsets) — no zero-init required anywhere
  float* G     = ws;                      // 65536            -> 65536
  float* XSUMP = ws + 65536;              // 4096             -> 69632
  float* RMAX  = ws + 69632;              // 1024             -> 70656
  float* RSUM  = ws + 70656;              // 1024             -> 71680
  float* AV    = ws + 71680;              // 1024             -> 72704
  float* BVa   = ws + 72704;              // 1024             -> 73728
  float* AQ    = ws + 73728;              // 16               -> 73744
  float* BQa   = ws + 73744;              // 16 (pad)         -> 73984
  float* CTX   = ws + 73984;              // 65536            -> 139520
  float* XPP   = ws + 139520;             // 4194304          -> 4333824
  float* KB    = ws + 4333824;            // 4194304          -> 8528128
  float* QB    = ws + 8528128;            // 1048576          -> 9576704
  u32*  PART   = (u32*)(ws + 139520);     // 8388608 u32, aliases XPP+KB (disjoint lifetime:
                                          // k_gxx/k_gred finish before k_proj/k_xp write)
  unsigned short* XBF = (unsigned short*)(ws + 9576704);  // 16777216 bf16 -> ends 17965312 (71.9 MB)

  k_cvt   <<<4096, 256, 0, stream>>>(x, XBF, XSUMP);
  k_gxx   <<<256,  512, 0, stream>>>(XBF, PART);
  k_gred  <<<128,  256, 0, stream>>>(PART, G);
  k_proj  <<<512,  256, 0, stream>>>(XBF, Wq, bq, Wk, bk, KB, QB);
  k_sstats<<<1024, 256, 0, stream>>>(KB, RMAX, RSUM);
  k_fin   <<<1040, 256, 0, stream>>>(G, XSUMP, Wv, bv, gv, btv, Wq, bq, gq, btq,
                                     AV, BVa, AQ, BQa);
  k_xp    <<<256,  256, 0, stream>>>(XBF, KB, RMAX, XPP);
  k_ctx   <<<256,  256, 0, stream>>>(XPP, RSUM, Wv, bv, AV, BVa, CTX);
  k_y     <<<256,  256, 0, stream>>>(QB, CTX, AQ, BQa, out);
}

// Round 7
// 161.165 us; speedup vs baseline: 2.2756x; 1.1614x over previous
//
#include <hip/hip_runtime.h>
#include <hip/hip_bf16.h>

typedef short s16x8 __attribute__((ext_vector_type(8)));
typedef short s16x4 __attribute__((ext_vector_type(4)));
typedef float f32x4 __attribute__((ext_vector_type(4)));
typedef unsigned u32;
typedef u32 u32x2 __attribute__((ext_vector_type(2)));

#define DI __device__ __forceinline__

constexpr int BB = 16;    // batch
constexpr int CC = 256;   // in channels
constexpr int MM = 4096;  // H*W
constexpr int KD = 16;    // k
constexpr int UK = 64;    // u*k
constexpr float EPSV = 1e-5f;

DI unsigned short f2bf(float f) {
  union { float f; unsigned u; } v; v.f = f;
  unsigned r = v.u + 0x7FFFu + ((v.u >> 16) & 1u);
  return (unsigned short)(r >> 16);
}
DI float bflo(u32 v) { union { u32 u; float f; } w; w.u = v << 16; return w.f; }
DI float bfhi(u32 v) { union { u32 u; float f; } w; w.u = v & 0xFFFF0000u; return w.f; }

// ---- streaming convert x f32 -> bf16, per-(b,c) partial sum (no atomics) ----
__global__ __launch_bounds__(256) void k_cvt(const float* __restrict__ x,
    unsigned short* __restrict__ xbf, float* __restrict__ xsump) {
  int bid = blockIdx.x;                 // b*256 + c
  size_t base = (size_t)bid * MM;
  int t = threadIdx.x;
  float s = 0.f;
#pragma unroll
  for (int i = 0; i < 4; ++i) {
    size_t idx = base + (size_t)(i * 256 + t) * 4;
    float4 v = *(const float4*)(x + idx);
    s16x4 c;
    c[0] = (short)f2bf(v.x); c[1] = (short)f2bf(v.y);
    c[2] = (short)f2bf(v.z); c[3] = (short)f2bf(v.w);
    *(s16x4*)&xbf[idx] = c;
    s += v.x + v.y + v.z + v.w;
  }
#pragma unroll
  for (int o = 32; o; o >>= 1) s += __shfl_down(s, o);
  __shared__ float red[4];
  if ((t & 63) == 0) red[t >> 6] = s;
  __syncthreads();
  if (t == 0) xsump[bid] = red[0] + red[1] + red[2] + red[3];
}

// ---- G-partial = X_chunk X_chunk^T (bf16 MFMA, double-buffered LDS) ----
// grid 256 = (b, mc of 256 m); 512 thr = 8 waves, wave tile 128x64
__global__ __launch_bounds__(512) void k_gxx(const unsigned short* __restrict__ xbf,
                                             u32* __restrict__ part) {
  int b = blockIdx.x >> 4, mc = blockIdx.x & 15;
  int m0 = mc * 256;
  __shared__ short lds[2][256 * 72];    // pitch 72 bf16 = 144B (16B-aligned rows)
  int t = threadIdx.x, w = t >> 6, l = t & 63;
  int wr = w >> 2, wc = w & 3;
  int lrow = l & 15, lk8 = (l >> 4) * 8;
  int srow = t >> 3, sseg = (t & 7) * 8;   // staging: 8 lanes cover one row's 128B

  const unsigned short* gsrc = xbf + ((size_t)(b * CC + srow)) * MM + m0 + sseg;

  s16x8 rg[4];
#pragma unroll
  for (int i = 0; i < 4; ++i)
    rg[i] = *(const s16x8*)(gsrc + (size_t)i * 64 * MM);
#pragma unroll
  for (int i = 0; i < 4; ++i)
    *(s16x8*)&lds[0][(srow + i * 64) * 72 + sseg] = rg[i];

  f32x4 acc[8][4];
#pragma unroll
  for (int i = 0; i < 8; ++i)
#pragma unroll
    for (int j = 0; j < 4; ++j) acc[i][j] = (f32x4)0.f;

#pragma unroll
  for (int ks = 0; ks < 4; ++ks) {
    __syncthreads();
    if (ks < 3) {   // issue next-step global loads early (overlap with MFMA below)
#pragma unroll
      for (int i = 0; i < 4; ++i)
        rg[i] = *(const s16x8*)(gsrc + (size_t)i * 64 * MM + (ks + 1) * 64);
    }
    int buf = ks & 1;
#pragma unroll
    for (int half = 0; half < 2; ++half) {
      s16x8 af[8], bf[4];
#pragma unroll
      for (int i = 0; i < 8; ++i)
        af[i] = *(const s16x8*)&lds[buf][(wr * 128 + i * 16 + lrow) * 72 + half * 32 + lk8];
#pragma unroll
      for (int j = 0; j < 4; ++j)
        bf[j] = *(const s16x8*)&lds[buf][(wc * 64 + j * 16 + lrow) * 72 + half * 32 + lk8];
#pragma unroll
      for (int i = 0; i < 8; ++i)
#pragma unroll
        for (int j = 0; j < 4; ++j)
          acc[i][j] = __builtin_amdgcn_mfma_f32_16x16x32_bf16(af[i], bf[j], acc[i][j], 0, 0, 0);
    }
    if (ks < 3) {   // write-late into the other buffer (safe: top sync separates)
#pragma unroll
      for (int i = 0; i < 4; ++i)
        *(s16x8*)&lds[buf ^ 1][(srow + i * 64) * 72 + sseg] = rg[i];
    }
  }

  // epilogue: packed bf16 partial, lane-minor flat layout (coalesced)
  size_t pb = (size_t)blockIdx.x * 32768;
#pragma unroll
  for (int i = 0; i < 8; ++i)
#pragma unroll
    for (int j = 0; j < 4; ++j) {
      int tau = (w * 8 + i) * 4 + j;
      u32x2 pk;
      pk[0] = (u32)f2bf(acc[i][j][0]) | ((u32)f2bf(acc[i][j][1]) << 16);
      pk[1] = (u32)f2bf(acc[i][j][2]) | ((u32)f2bf(acc[i][j][3]) << 16);
      *(u32x2*)&part[pb + tau * 128 + l * 2] = pk;
    }
}

// ---- reduce 256 G-partials -> G ----
__global__ __launch_bounds__(256) void k_gred(const u32* __restrict__ part,
                                              float* __restrict__ G) {
  int q = blockIdx.x * 256 + threadIdx.x;   // 0..32767
  float s0 = 0.f, s1 = 0.f;
#pragma unroll 8
  for (int p = 0; p < 256; ++p) {
    u32 v = part[(size_t)p * 32768 + q];
    s0 += bflo(v);
    s1 += bfhi(v);
  }
  int r2 = q & 1, l = (q >> 1) & 63, tau = q >> 7;
  int j = tau & 3, i = (tau >> 2) & 7, w = tau >> 5;
  int wr = w >> 2, wc = w & 3;
  int row = wr * 128 + i * 16 + (l >> 4) * 4 + r2 * 2;
  int col = wc * 64 + j * 16 + (l & 15);
  G[row * 256 + col] = s0;
  G[(row + 1) * 256 + col] = s1;
}

// ---------------- Q/K projection via bf16 MFMA (reads bf16 x) ----------------
__global__ __launch_bounds__(256) void k_proj(const unsigned short* __restrict__ xbf,
    const float* __restrict__ Wq, const float* __restrict__ bq,
    const float* __restrict__ Wk, const float* __restrict__ bk,
    float* __restrict__ Kb, float* __restrict__ Qb) {
  int b = blockIdx.x >> 5, mc = blockIdx.x & 31;   // 16 b * 32 m-chunks
  int gm0 = mc * 128;
  __shared__ short wlds[80 * 264];                 // W bf16, pitch 264
  __shared__ u32 xt[128 * 17];                     // x^T tile: [m][c-pair], pitch 17
  int t = threadIdx.x;
  int w = t >> 6, l = t & 63;
  int lrow = l & 15, lk = l >> 4;                  // lk in 0..3

#pragma unroll 4
  for (int o = 0; o < 80; ++o) {
    float v = (o < 64) ? Wk[o * CC + t] : Wq[(o - 64) * CC + t];
    wlds[o * 264 + t] = (short)f2bf(v);
  }

  f32x4 acc[5][2];
#pragma unroll
  for (int i = 0; i < 5; ++i) { acc[i][0] = (f32x4)0.f; acc[i][1] = (f32x4)0.f; }

  int c2 = t >> 4;          // c-pair column 0..15
  int mq = t & 15;          // m quad index

  for (int ks = 0; ks < 8; ++ks) {
    int c0 = ks * 32;
    __syncthreads();
#pragma unroll
    for (int mb = 0; mb < 128; mb += 64) {
      int m = mb + mq * 4;
      const unsigned short* p0 = xbf + ((size_t)(b * CC + c0 + 2 * c2)) * MM + gm0 + m;
      s16x4 v0 = *(const s16x4*)p0;
      s16x4 v1 = *(const s16x4*)(p0 + MM);
      xt[(m + 0) * 17 + c2] = (u32)(unsigned short)v0[0] | ((u32)(unsigned short)v1[0] << 16);
      xt[(m + 1) * 17 + c2] = (u32)(unsigned short)v0[1] | ((u32)(unsigned short)v1[1] << 16);
      xt[(m + 2) * 17 + c2] = (u32)(unsigned short)v0[2] | ((u32)(unsigned short)v1[2] << 16);
      xt[(m + 3) * 17 + c2] = (u32)(unsigned short)v0[3] | ((u32)(unsigned short)v1[3] << 16);
    }
    __syncthreads();
    union { s16x8 v; u32 wd[4]; } bfr[2];
#pragma unroll
    for (int j = 0; j < 2; ++j) {
      int ml = w * 32 + j * 16 + lrow;
#pragma unroll
      for (int i = 0; i < 4; ++i) bfr[j].wd[i] = xt[ml * 17 + lk * 4 + i];
    }
#pragma unroll
    for (int ot = 0; ot < 5; ++ot) {
      s16x8 af = *(const s16x8*)&wlds[(ot * 16 + lrow) * 264 + c0 + lk * 8];
      acc[ot][0] = __builtin_amdgcn_mfma_f32_16x16x32_bf16(af, bfr[0].v, acc[ot][0], 0, 0, 0);
      acc[ot][1] = __builtin_amdgcn_mfma_f32_16x16x32_bf16(af, bfr[1].v, acc[ot][1], 0, 0, 0);
    }
  }

#pragma unroll
  for (int ot = 0; ot < 5; ++ot)
#pragma unroll
    for (int j = 0; j < 2; ++j)
#pragma unroll
      for (int r = 0; r < 4; ++r) {
        int o = ot * 16 + lk * 4 + r;
        int m = gm0 + w * 32 + j * 16 + lrow;
        float val = acc[ot][j][r];
        if (o < 64) Kb[((size_t)(b * UK + o)) * MM + m] = val + bk[o];
        else        Qb[((size_t)(b * KD + o - 64)) * MM + m] = val + bq[o - 64];
      }
}

// ---------------- softmax row stats over K ----------------
__global__ __launch_bounds__(256) void k_sstats(const float* __restrict__ Kb,
    float* __restrict__ rmax, float* __restrict__ rsum) {
  int r = blockIdx.x;                    // 0..1023
  int t = threadIdx.x;
  const float4* p = (const float4*)(Kb + (size_t)r * MM);
  float4 v[4];
  float mx = -3.4e38f;
#pragma unroll
  for (int i = 0; i < 4; ++i) {
    v[i] = p[i * 256 + t];
    mx = fmaxf(mx, fmaxf(fmaxf(v[i].x, v[i].y), fmaxf(v[i].z, v[i].w)));
  }
#pragma unroll
  for (int o = 32; o; o >>= 1) mx = fmaxf(mx, __shfl_xor(mx, o));
  __shared__ float red[4];
  int w = t >> 6;
  if ((t & 63) == 0) red[w] = mx;
  __syncthreads();
  mx = fmaxf(fmaxf(red[0], red[1]), fmaxf(red[2], red[3]));
  float s = 0.f;
#pragma unroll
  for (int i = 0; i < 4; ++i)
    s += __expf(v[i].x - mx) + __expf(v[i].y - mx) +
         __expf(v[i].z - mx) + __expf(v[i].w - mx);
#pragma unroll
  for (int o = 32; o; o >>= 1) s += __shfl_xor(s, o);
  __syncthreads();
  if ((t & 63) == 0) red[w] = s;
  __syncthreads();
  if (t == 0) {
    rmax[r] = mx;
    rsum[r] = red[0] + red[1] + red[2] + red[3];
  }
}

// ---- BN affine params: 4 channels/block, coalesced row-streamed G ----
// qf_o = sum_{r,c} w_r G_rc w_c ; wave w owns rows r===w (mod 4), lane l owns cols 4l..4l+3
__global__ __launch_bounds__(256) void k_fin(const float* __restrict__ G,
    const float* __restrict__ xsump,
    const float* __restrict__ Wv, const float* __restrict__ bv,
    const float* __restrict__ gv, const float* __restrict__ btv,
    const float* __restrict__ Wq, const float* __restrict__ bq,
    const float* __restrict__ gq, const float* __restrict__ btq,
    float* __restrict__ AV, float* __restrict__ BVa,
    float* __restrict__ AQ, float* __restrict__ BQa) {
  int t = threadIdx.x, w = t >> 6, l = t & 63;
  int o0 = blockIdx.x * 4;                  // grid 260 -> channels o0..o0+3
  __shared__ float lw[4][256];
#pragma unroll
  for (int oo = 0; oo < 4; ++oo) {
    int o = o0 + oo;
    lw[oo][t] = (o < 1024) ? Wv[(size_t)o * CC + t] : Wq[(size_t)(o - 1024) * CC + t];
  }
  __syncthreads();

  float4 w4[4];
#pragma unroll
  for (int oo = 0; oo < 4; ++oo) w4[oo] = *(const float4*)&lw[oo][4 * l];

  float qf[4] = {0.f, 0.f, 0.f, 0.f};
#pragma unroll 4
  for (int i = 0; i < 64; ++i) {
    int r = i * 4 + w;
    float4 g4 = *(const float4*)(G + (size_t)r * CC + 4 * l);   // coalesced: wave reads 1 row
#pragma unroll
    for (int oo = 0; oo < 4; ++oo) {
      float d = g4.x * w4[oo].x + g4.y * w4[oo].y + g4.z * w4[oo].z + g4.w * w4[oo].w;
      qf[oo] = fmaf(lw[oo][r], d, qf[oo]);
    }
  }

  float xs = 0.f;
#pragma unroll
  for (int bb = 0; bb < 16; ++bb) xs += xsump[bb * 256 + t];
  float sx[4];
#pragma unroll
  for (int oo = 0; oo < 4; ++oo) sx[oo] = lw[oo][t] * xs;

#pragma unroll
  for (int oo = 0; oo < 4; ++oo)
#pragma unroll
    for (int od = 32; od; od >>= 1) {
      qf[oo] += __shfl_xor(qf[oo], od);
      sx[oo] += __shfl_xor(sx[oo], od);
    }
  __shared__ float rq[4][4], rs[4][4];
  if (l == 0)
#pragma unroll
    for (int oo = 0; oo < 4; ++oo) { rq[w][oo] = qf[oo]; rs[w][oo] = sx[oo]; }
  __syncthreads();
  if (t < 4) {
    int oo = t, o = o0 + oo;
    float q = rq[0][oo] + rq[1][oo] + rq[2][oo] + rq[3][oo];
    float s = rs[0][oo] + rs[1][oo] + rs[2][oo] + rs[3][oo];
    float bias, gamma, beta; float *pa, *pb;
    if (o < 1024) { bias = bv[o]; gamma = gv[o]; beta = btv[o]; pa = AV + o; pb = BVa + o; }
    else { int oi = o - 1024; bias = bq[oi]; gamma = gq[oi]; beta = btq[oi]; pa = AQ + oi; pb = BQa + oi; }
    const float invN = 1.f / 65536.f;
    float mean = s * invN + bias;
    float e2 = q * invN + 2.f * bias * s * invN + bias * bias;
    float var = e2 - mean * mean;
    float a = gamma * rsqrtf(var + EPSV);
    *pa = a;
    *pb = beta - mean * a;
  }
}

// ---- xp-partial[b,kc,j,c] = sum_{m in kc} exp(K-rmax) * x  (no atomics) ----
__global__ __launch_bounds__(256) void k_xp(const unsigned short* __restrict__ xbf,
    const float* __restrict__ Kb, const float* __restrict__ rmax,
    float* __restrict__ xpp) {
  int b = blockIdx.x >> 4, kc = blockIdx.x & 15;
  int kbase = kc * 256;
  __shared__ short la[64][40];
  __shared__ short lb[256][40];
  int t = threadIdx.x, w = t >> 6, l = t & 63;
  int lrow = l & 15, lk = (l >> 4) * 8;

  f32x4 acc[4][4];
#pragma unroll
  for (int i = 0; i < 4; ++i)
#pragma unroll
    for (int j = 0; j < 4; ++j) acc[i][j] = (f32x4)0.f;

  for (int ks = 0; ks < 8; ++ks) {
    int k0 = kbase + ks * 32;
    __syncthreads();
    {   // stage A: exp(K - rmax), 64 rows x 32 (K is f32)
      int r = t >> 2, sg = (t & 3) * 8;
      const float4* src = (const float4*)(Kb + ((size_t)(b * UK + r)) * MM + k0 + sg);
      float rm = rmax[b * UK + r];
      s16x8 wv;
#pragma unroll
      for (int i = 0; i < 2; ++i) {
        float4 v = src[i];
        wv[i * 4 + 0] = (short)f2bf(__expf(v.x - rm));
        wv[i * 4 + 1] = (short)f2bf(__expf(v.y - rm));
        wv[i * 4 + 2] = (short)f2bf(__expf(v.z - rm));
        wv[i * 4 + 3] = (short)f2bf(__expf(v.w - rm));
      }
      *(s16x8*)&la[r][sg] = wv;
    }
#pragma unroll
    for (int i = 0; i < 4; ++i) {   // stage B: bf16 x, 256 rows x 32
      int r = i * 64 + (t >> 2), sg = (t & 3) * 8;
      s16x8 v = *(const s16x8*)&xbf[((size_t)(b * CC + r)) * MM + k0 + sg];
      *(s16x8*)&lb[r][sg] = v;
    }
    __syncthreads();
    s16x8 af[4], bfr[4];
#pragma unroll
    for (int i = 0; i < 4; ++i) af[i] = *(const s16x8*)&la[i * 16 + lrow][lk];
#pragma unroll
    for (int j = 0; j < 4; ++j) bfr[j] = *(const s16x8*)&lb[w * 64 + j * 16 + lrow][lk];
#pragma unroll
    for (int i = 0; i < 4; ++i)
#pragma unroll
      for (int j = 0; j < 4; ++j)
        acc[i][j] = __builtin_amdgcn_mfma_f32_16x16x32_bf16(af[i], bfr[j], acc[i][j], 0, 0, 0);
  }
  float* dst = xpp + (size_t)blockIdx.x * UK * CC;
#pragma unroll
  for (int i = 0; i < 4; ++i)
#pragma unroll
    for (int j = 0; j < 4; ++j)
#pragma unroll
      for (int r = 0; r < 4; ++r) {
        int row = i * 16 + (l >> 4) * 4 + r;       // j index 0..63
        int col = w * 64 + j * 16 + lrow;          // c index 0..255
        dst[row * 256 + col] = acc[i][j][r];
      }
}

// ---- ctx[b,kk,vv] = sum_u aV*(Wv . xp_n + bv) + bVa  (reduces kc-partials) ----
__global__ __launch_bounds__(256) void k_ctx(const float* __restrict__ xpp,
    const float* __restrict__ rsum,
    const float* __restrict__ Wv, const float* __restrict__ bv,
    const float* __restrict__ AV, const float* __restrict__ BVa,
    float* __restrict__ CTX) {
  int b = blockIdx.x >> 4, kk = blockIdx.x & 15;
  __shared__ float lxp[4][256];
  int t = threadIdx.x;
#pragma unroll
  for (int u = 0; u < 4; ++u) {
    int row = u * KD + kk;
    float s = 0.f;
#pragma unroll
    for (int kc = 0; kc < 16; ++kc)
      s += xpp[((size_t)(b * 16 + kc) * UK + row) * CC + t];
    lxp[u][t] = s / rsum[b * UK + row];
  }
  __syncthreads();
  float acc = 0.f;
#pragma unroll
  for (int u = 0; u < 4; ++u) {
    int ch = u * 256 + t;
    const float4* wv4 = (const float4*)(Wv + (size_t)ch * CC);
    float dot = 0.f;
#pragma unroll 8
    for (int c4 = 0; c4 < 64; ++c4) {
      float4 wv = wv4[c4];
      dot += wv.x * lxp[u][c4 * 4 + 0] + wv.y * lxp[u][c4 * 4 + 1] +
             wv.z * lxp[u][c4 * 4 + 2] + wv.w * lxp[u][c4 * 4 + 3];
    }
    acc += AV[ch] * (dot + bv[ch]) + BVa[ch];
  }
  CTX[((size_t)b * KD + kk) * 256 + t] = acc;
}

// ---------------- y[b,vv,m] = sum_kk (aQ*Q+bQ)[kk,m] * ctx[kk,vv] ----------------
__global__ __launch_bounds__(256) void k_y(const float* __restrict__ Qb,
    const float* __restrict__ CTX,
    const float* __restrict__ AQ, const float* __restrict__ BQa,
    float* __restrict__ y) {
  int b = blockIdx.x >> 4, nc = blockIdx.x & 15;
  int m = nc * 256 + threadIdx.x;
  float qn[16];
#pragma unroll
  for (int kk = 0; kk < 16; ++kk)
    qn[kk] = AQ[kk] * Qb[((size_t)b * KD + kk) * MM + m] + BQa[kk];
  const float* cb = CTX + (size_t)b * KD * 256;
  float* yo = y + (size_t)b * 256 * MM + m;
#pragma unroll 4
  for (int vv = 0; vv < 256; ++vv) {
    float acc = 0.f;
#pragma unroll
    for (int kk = 0; kk < 16; ++kk)
      acc = fmaf(qn[kk], cb[kk * 256 + vv], acc);   // uniform -> scalar loads
    yo[(size_t)vv * MM] = acc;
  }
}

extern "C" void kernel_launch(void* const* d_in, const int* in_sizes, int n_in,
                              void* d_out, int out_size, void* d_ws, size_t ws_size,
                              hipStream_t stream) {
  const float* x   = (const float*)d_in[0];
  const float* Wq  = (const float*)d_in[1];
  const float* bq  = (const float*)d_in[2];
  const float* Wk  = (const float*)d_in[3];
  const float* bk  = (const float*)d_in[4];
  const float* Wv  = (const float*)d_in[5];
  const float* bv  = (const float*)d_in[6];
  const float* gq  = (const float*)d_in[7];
  const float* btq = (const float*)d_in[8];
  const float* gv  = (const float*)d_in[9];
  const float* btv = (const float*)d_in[10];
  float* out = (float*)d_out;
  float* ws  = (float*)d_ws;

  // workspace layout (f32-element offsets) — no zero-init required anywhere
  float* G     = ws;                      // 65536            -> 65536
  float* XSUMP = ws + 65536;              // 4096             -> 69632
  float* RMAX  = ws + 69632;              // 1024             -> 70656
  float* RSUM  = ws + 70656;              // 1024             -> 71680
  float* AV    = ws + 71680;              // 1024             -> 72704
  float* BVa   = ws + 72704;              // 1024             -> 73728
  float* AQ    = ws + 73728;              // 16               -> 73744
  float* BQa   = ws + 73744;              // 16 (pad)         -> 73984
  float* CTX   = ws + 73984;              // 65536            -> 139520
  float* XPP   = ws + 139520;             // 4194304          -> 4333824
  float* KB    = ws + 4333824;            // 4194304          -> 8528128
  float* QB    = ws + 8528128;            // 1048576          -> 9576704
  u32*  PART   = (u32*)(ws + 139520);     // 8388608 u32, aliases XPP+KB (disjoint lifetime:
                                          // k_gxx/k_gred finish before k_proj/k_xp write)
  unsigned short* XBF = (unsigned short*)(ws + 9576704);  // 16777216 bf16 -> ends 17965312 (71.9 MB)

  k_cvt   <<<4096, 256, 0, stream>>>(x, XBF, XSUMP);
  k_gxx   <<<256,  512, 0, stream>>>(XBF, PART);
  k_gred  <<<128,  256, 0, stream>>>(PART, G);
  k_proj  <<<512,  256, 0, stream>>>(XBF, Wq, bq, Wk, bk, KB, QB);
  k_sstats<<<1024, 256, 0, stream>>>(KB, RMAX, RSUM);
  k_fin   <<<260,  256, 0, stream>>>(G, XSUMP, Wv, bv, gv, btv, Wq, bq, gq, btq,
                                     AV, BVa, AQ, BQa);
  k_xp    <<<256,  256, 0, stream>>>(XBF, KB, RMAX, XPP);
  k_ctx   <<<256,  256, 0, stream>>>(XPP, RSUM, Wv, bv, AV, BVa, CTX);
  k_y     <<<256,  256, 0, stream>>>(QB, CTX, AQ, BQa, out);
}

// Round 8
// 145.536 us; speedup vs baseline: 2.5200x; 1.1074x over previous
//
#include <hip/hip_runtime.h>
#include <hip/hip_bf16.h>

typedef short s16x8 __attribute__((ext_vector_type(8)));
typedef short s16x4 __attribute__((ext_vector_type(4)));
typedef float f32x4 __attribute__((ext_vector_type(4)));
typedef unsigned u32;
typedef u32 u32x2 __attribute__((ext_vector_type(2)));

#define DI __device__ __forceinline__

constexpr int BB = 16;    // batch
constexpr int CC = 256;   // in channels
constexpr int MM = 4096;  // H*W
constexpr int KD = 16;    // k
constexpr int UK = 64;    // u*k
constexpr float EPSV = 1e-5f;

DI unsigned short f2bf(float f) {
  union { float f; unsigned u; } v; v.f = f;
  unsigned r = v.u + 0x7FFFu + ((v.u >> 16) & 1u);
  return (unsigned short)(r >> 16);
}
DI float bflo(u32 v) { union { u32 u; float f; } w; w.u = v << 16; return w.f; }
DI float bfhi(u32 v) { union { u32 u; float f; } w; w.u = v & 0xFFFF0000u; return w.f; }

// ---- streaming convert x f32 -> bf16, per-(b,c) partial sum (no atomics) ----
__global__ __launch_bounds__(256) void k_cvt(const float* __restrict__ x,
    unsigned short* __restrict__ xbf, float* __restrict__ xsump) {
  int bid = blockIdx.x;                 // b*256 + c
  size_t base = (size_t)bid * MM;
  int t = threadIdx.x;
  float s = 0.f;
#pragma unroll
  for (int i = 0; i < 4; ++i) {
    size_t idx = base + (size_t)(i * 256 + t) * 4;
    float4 v = *(const float4*)(x + idx);
    s16x4 c;
    c[0] = (short)f2bf(v.x); c[1] = (short)f2bf(v.y);
    c[2] = (short)f2bf(v.z); c[3] = (short)f2bf(v.w);
    *(s16x4*)&xbf[idx] = c;
    s += v.x + v.y + v.z + v.w;
  }
#pragma unroll
  for (int o = 32; o; o >>= 1) s += __shfl_down(s, o);
  __shared__ float red[4];
  if ((t & 63) == 0) red[t >> 6] = s;
  __syncthreads();
  if (t == 0) xsump[bid] = red[0] + red[1] + red[2] + red[3];
}

// ---- G-partial = X_chunk X_chunk^T (bf16 MFMA, double-buffered LDS) ----
__global__ __launch_bounds__(512) void k_gxx(const unsigned short* __restrict__ xbf,
                                             u32* __restrict__ part) {
  int b = blockIdx.x >> 4, mc = blockIdx.x & 15;
  int m0 = mc * 256;
  __shared__ short lds[2][256 * 72];    // pitch 72 bf16 = 144B
  int t = threadIdx.x, w = t >> 6, l = t & 63;
  int wr = w >> 2, wc = w & 3;
  int lrow = l & 15, lk8 = (l >> 4) * 8;
  int srow = t >> 3, sseg = (t & 7) * 8;

  const unsigned short* gsrc = xbf + ((size_t)(b * CC + srow)) * MM + m0 + sseg;

  s16x8 rg[4];
#pragma unroll
  for (int i = 0; i < 4; ++i)
    rg[i] = *(const s16x8*)(gsrc + (size_t)i * 64 * MM);
#pragma unroll
  for (int i = 0; i < 4; ++i)
    *(s16x8*)&lds[0][(srow + i * 64) * 72 + sseg] = rg[i];

  f32x4 acc[8][4];
#pragma unroll
  for (int i = 0; i < 8; ++i)
#pragma unroll
    for (int j = 0; j < 4; ++j) acc[i][j] = (f32x4)0.f;

#pragma unroll
  for (int ks = 0; ks < 4; ++ks) {
    __syncthreads();
    if (ks < 3) {
#pragma unroll
      for (int i = 0; i < 4; ++i)
        rg[i] = *(const s16x8*)(gsrc + (size_t)i * 64 * MM + (ks + 1) * 64);
    }
    int buf = ks & 1;
#pragma unroll
    for (int half = 0; half < 2; ++half) {
      s16x8 af[8], bf[4];
#pragma unroll
      for (int i = 0; i < 8; ++i)
        af[i] = *(const s16x8*)&lds[buf][(wr * 128 + i * 16 + lrow) * 72 + half * 32 + lk8];
#pragma unroll
      for (int j = 0; j < 4; ++j)
        bf[j] = *(const s16x8*)&lds[buf][(wc * 64 + j * 16 + lrow) * 72 + half * 32 + lk8];
#pragma unroll
      for (int i = 0; i < 8; ++i)
#pragma unroll
        for (int j = 0; j < 4; ++j)
          acc[i][j] = __builtin_amdgcn_mfma_f32_16x16x32_bf16(af[i], bf[j], acc[i][j], 0, 0, 0);
    }
    if (ks < 3) {
#pragma unroll
      for (int i = 0; i < 4; ++i)
        *(s16x8*)&lds[buf ^ 1][(srow + i * 64) * 72 + sseg] = rg[i];
    }
  }

  size_t pb = (size_t)blockIdx.x * 32768;
#pragma unroll
  for (int i = 0; i < 8; ++i)
#pragma unroll
    for (int j = 0; j < 4; ++j) {
      int tau = (w * 8 + i) * 4 + j;
      u32x2 pk;
      pk[0] = (u32)f2bf(acc[i][j][0]) | ((u32)f2bf(acc[i][j][1]) << 16);
      pk[1] = (u32)f2bf(acc[i][j][2]) | ((u32)f2bf(acc[i][j][3]) << 16);
      *(u32x2*)&part[pb + tau * 128 + l * 2] = pk;
    }
}

// ---- reduce 256 G-partials -> G ----
__global__ __launch_bounds__(256) void k_gred(const u32* __restrict__ part,
                                              float* __restrict__ G) {
  int q = blockIdx.x * 256 + threadIdx.x;   // 0..32767
  float s0 = 0.f, s1 = 0.f;
#pragma unroll 8
  for (int p = 0; p < 256; ++p) {
    u32 v = part[(size_t)p * 32768 + q];
    s0 += bflo(v);
    s1 += bfhi(v);
  }
  int r2 = q & 1, l = (q >> 1) & 63, tau = q >> 7;
  int j = tau & 3, i = (tau >> 2) & 7, w = tau >> 5;
  int wr = w >> 2, wc = w & 3;
  int row = wr * 128 + i * 16 + (l >> 4) * 4 + r2 * 2;
  int col = wc * 64 + j * 16 + (l & 15);
  G[row * 256 + col] = s0;
  G[(row + 1) * 256 + col] = s1;
}

// ---------------- Q/K projection via bf16 MFMA (reads bf16 x) ----------------
__global__ __launch_bounds__(256) void k_proj(const unsigned short* __restrict__ xbf,
    const float* __restrict__ Wq, const float* __restrict__ bq,
    const float* __restrict__ Wk, const float* __restrict__ bk,
    float* __restrict__ Kb, float* __restrict__ Qb) {
  int b = blockIdx.x >> 5, mc = blockIdx.x & 31;   // 16 b * 32 m-chunks
  int gm0 = mc * 128;
  __shared__ short wlds[80 * 264];
  __shared__ u32 xt[128 * 17];
  int t = threadIdx.x;
  int w = t >> 6, l = t & 63;
  int lrow = l & 15, lk = l >> 4;

#pragma unroll 4
  for (int o = 0; o < 80; ++o) {
    float v = (o < 64) ? Wk[o * CC + t] : Wq[(o - 64) * CC + t];
    wlds[o * 264 + t] = (short)f2bf(v);
  }

  f32x4 acc[5][2];
#pragma unroll
  for (int i = 0; i < 5; ++i) { acc[i][0] = (f32x4)0.f; acc[i][1] = (f32x4)0.f; }

  int c2 = t >> 4;
  int mq = t & 15;

  for (int ks = 0; ks < 8; ++ks) {
    int c0 = ks * 32;
    __syncthreads();
#pragma unroll
    for (int mb = 0; mb < 128; mb += 64) {
      int m = mb + mq * 4;
      const unsigned short* p0 = xbf + ((size_t)(b * CC + c0 + 2 * c2)) * MM + gm0 + m;
      s16x4 v0 = *(const s16x4*)p0;
      s16x4 v1 = *(const s16x4*)(p0 + MM);
      xt[(m + 0) * 17 + c2] = (u32)(unsigned short)v0[0] | ((u32)(unsigned short)v1[0] << 16);
      xt[(m + 1) * 17 + c2] = (u32)(unsigned short)v0[1] | ((u32)(unsigned short)v1[1] << 16);
      xt[(m + 2) * 17 + c2] = (u32)(unsigned short)v0[2] | ((u32)(unsigned short)v1[2] << 16);
      xt[(m + 3) * 17 + c2] = (u32)(unsigned short)v0[3] | ((u32)(unsigned short)v1[3] << 16);
    }
    __syncthreads();
    union { s16x8 v; u32 wd[4]; } bfr[2];
#pragma unroll
    for (int j = 0; j < 2; ++j) {
      int ml = w * 32 + j * 16 + lrow;
#pragma unroll
      for (int i = 0; i < 4; ++i) bfr[j].wd[i] = xt[ml * 17 + lk * 4 + i];
    }
#pragma unroll
    for (int ot = 0; ot < 5; ++ot) {
      s16x8 af = *(const s16x8*)&wlds[(ot * 16 + lrow) * 264 + c0 + lk * 8];
      acc[ot][0] = __builtin_amdgcn_mfma_f32_16x16x32_bf16(af, bfr[0].v, acc[ot][0], 0, 0, 0);
      acc[ot][1] = __builtin_amdgcn_mfma_f32_16x16x32_bf16(af, bfr[1].v, acc[ot][1], 0, 0, 0);
    }
  }

#pragma unroll
  for (int ot = 0; ot < 5; ++ot)
#pragma unroll
    for (int j = 0; j < 2; ++j)
#pragma unroll
      for (int r = 0; r < 4; ++r) {
        int o = ot * 16 + lk * 4 + r;
        int m = gm0 + w * 32 + j * 16 + lrow;
        float val = acc[ot][j][r];
        if (o < 64) Kb[((size_t)(b * UK + o)) * MM + m] = val + bk[o];
        else        Qb[((size_t)(b * KD + o - 64)) * MM + m] = val + bq[o - 64];
      }
}

// ---------------- softmax row stats over K ----------------
__global__ __launch_bounds__(256) void k_sstats(const float* __restrict__ Kb,
    float* __restrict__ rmax, float* __restrict__ rsum) {
  int r = blockIdx.x;                    // 0..1023
  int t = threadIdx.x;
  const float4* p = (const float4*)(Kb + (size_t)r * MM);
  float4 v[4];
  float mx = -3.4e38f;
#pragma unroll
  for (int i = 0; i < 4; ++i) {
    v[i] = p[i * 256 + t];
    mx = fmaxf(mx, fmaxf(fmaxf(v[i].x, v[i].y), fmaxf(v[i].z, v[i].w)));
  }
#pragma unroll
  for (int o = 32; o; o >>= 1) mx = fmaxf(mx, __shfl_xor(mx, o));
  __shared__ float red[4];
  int w = t >> 6;
  if ((t & 63) == 0) red[w] = mx;
  __syncthreads();
  mx = fmaxf(fmaxf(red[0], red[1]), fmaxf(red[2], red[3]));
  float s = 0.f;
#pragma unroll
  for (int i = 0; i < 4; ++i)
    s += __expf(v[i].x - mx) + __expf(v[i].y - mx) +
         __expf(v[i].z - mx) + __expf(v[i].w - mx);
#pragma unroll
  for (int o = 32; o; o >>= 1) s += __shfl_xor(s, o);
  __syncthreads();
  if ((t & 63) == 0) red[w] = s;
  __syncthreads();
  if (t == 0) {
    rmax[r] = mx;
    rsum[r] = red[0] + red[1] + red[2] + red[3];
  }
}

// ---- BN affine params: 4 channels/block, coalesced row-streamed G ----
__global__ __launch_bounds__(256) void k_fin(const float* __restrict__ G,
    const float* __restrict__ xsump,
    const float* __restrict__ Wv, const float* __restrict__ bv,
    const float* __restrict__ gv, const float* __restrict__ btv,
    const float* __restrict__ Wq, const float* __restrict__ bq,
    const float* __restrict__ gq, const float* __restrict__ btq,
    float* __restrict__ AV, float* __restrict__ BVa,
    float* __restrict__ AQ, float* __restrict__ BQa) {
  int t = threadIdx.x, w = t >> 6, l = t & 63;
  int o0 = blockIdx.x * 4;
  __shared__ float lw[4][256];
#pragma unroll
  for (int oo = 0; oo < 4; ++oo) {
    int o = o0 + oo;
    lw[oo][t] = (o < 1024) ? Wv[(size_t)o * CC + t] : Wq[(size_t)(o - 1024) * CC + t];
  }
  __syncthreads();

  float4 w4[4];
#pragma unroll
  for (int oo = 0; oo < 4; ++oo) w4[oo] = *(const float4*)&lw[oo][4 * l];

  float qf[4] = {0.f, 0.f, 0.f, 0.f};
#pragma unroll 4
  for (int i = 0; i < 64; ++i) {
    int r = i * 4 + w;
    float4 g4 = *(const float4*)(G + (size_t)r * CC + 4 * l);
#pragma unroll
    for (int oo = 0; oo < 4; ++oo) {
      float d = g4.x * w4[oo].x + g4.y * w4[oo].y + g4.z * w4[oo].z + g4.w * w4[oo].w;
      qf[oo] = fmaf(lw[oo][r], d, qf[oo]);
    }
  }

  float xs = 0.f;
#pragma unroll
  for (int bb = 0; bb < 16; ++bb) xs += xsump[bb * 256 + t];
  float sx[4];
#pragma unroll
  for (int oo = 0; oo < 4; ++oo) sx[oo] = lw[oo][t] * xs;

#pragma unroll
  for (int oo = 0; oo < 4; ++oo)
#pragma unroll
    for (int od = 32; od; od >>= 1) {
      qf[oo] += __shfl_xor(qf[oo], od);
      sx[oo] += __shfl_xor(sx[oo], od);
    }
  __shared__ float rq[4][4], rs[4][4];
  if (l == 0)
#pragma unroll
    for (int oo = 0; oo < 4; ++oo) { rq[w][oo] = qf[oo]; rs[w][oo] = sx[oo]; }
  __syncthreads();
  if (t < 4) {
    int oo = t, o = o0 + oo;
    float q = rq[0][oo] + rq[1][oo] + rq[2][oo] + rq[3][oo];
    float s = rs[0][oo] + rs[1][oo] + rs[2][oo] + rs[3][oo];
    float bias, gamma, beta; float *pa, *pb;
    if (o < 1024) { bias = bv[o]; gamma = gv[o]; beta = btv[o]; pa = AV + o; pb = BVa + o; }
    else { int oi = o - 1024; bias = bq[oi]; gamma = gq[oi]; beta = btq[oi]; pa = AQ + oi; pb = BQa + oi; }
    const float invN = 1.f / 65536.f;
    float mean = s * invN + bias;
    float e2 = q * invN + 2.f * bias * s * invN + bias * bias;
    float var = e2 - mean * mean;
    float a = gamma * rsqrtf(var + EPSV);
    *pa = a;
    *pb = beta - mean * a;
  }
}

// ---- xp-partial[b,kc,j,c] = sum_{m in kc} exp(K-rmax) * x  (no atomics) ----
__global__ __launch_bounds__(256) void k_xp(const unsigned short* __restrict__ xbf,
    const float* __restrict__ Kb, const float* __restrict__ rmax,
    float* __restrict__ xpp) {
  int b = blockIdx.x >> 4, kc = blockIdx.x & 15;
  int kbase = kc * 256;
  __shared__ short la[64][40];
  __shared__ short lb[256][40];
  int t = threadIdx.x, w = t >> 6, l = t & 63;
  int lrow = l & 15, lk = (l >> 4) * 8;

  f32x4 acc[4][4];
#pragma unroll
  for (int i = 0; i < 4; ++i)
#pragma unroll
    for (int j = 0; j < 4; ++j) acc[i][j] = (f32x4)0.f;

  for (int ks = 0; ks < 8; ++ks) {
    int k0 = kbase + ks * 32;
    __syncthreads();
    {
      int r = t >> 2, sg = (t & 3) * 8;
      const float4* src = (const float4*)(Kb + ((size_t)(b * UK + r)) * MM + k0 + sg);
      float rm = rmax[b * UK + r];
      s16x8 wv;
#pragma unroll
      for (int i = 0; i < 2; ++i) {
        float4 v = src[i];
        wv[i * 4 + 0] = (short)f2bf(__expf(v.x - rm));
        wv[i * 4 + 1] = (short)f2bf(__expf(v.y - rm));
        wv[i * 4 + 2] = (short)f2bf(__expf(v.z - rm));
        wv[i * 4 + 3] = (short)f2bf(__expf(v.w - rm));
      }
      *(s16x8*)&la[r][sg] = wv;
    }
#pragma unroll
    for (int i = 0; i < 4; ++i) {
      int r = i * 64 + (t >> 2), sg = (t & 3) * 8;
      s16x8 v = *(const s16x8*)&xbf[((size_t)(b * CC + r)) * MM + k0 + sg];
      *(s16x8*)&lb[r][sg] = v;
    }
    __syncthreads();
    s16x8 af[4], bfr[4];
#pragma unroll
    for (int i = 0; i < 4; ++i) af[i] = *(const s16x8*)&la[i * 16 + lrow][lk];
#pragma unroll
    for (int j = 0; j < 4; ++j) bfr[j] = *(const s16x8*)&lb[w * 64 + j * 16 + lrow][lk];
#pragma unroll
    for (int i = 0; i < 4; ++i)
#pragma unroll
      for (int j = 0; j < 4; ++j)
        acc[i][j] = __builtin_amdgcn_mfma_f32_16x16x32_bf16(af[i], bfr[j], acc[i][j], 0, 0, 0);
  }
  float* dst = xpp + (size_t)blockIdx.x * UK * CC;
#pragma unroll
  for (int i = 0; i < 4; ++i)
#pragma unroll
    for (int j = 0; j < 4; ++j)
#pragma unroll
      for (int r = 0; r < 4; ++r) {
        int row = i * 16 + (l >> 4) * 4 + r;
        int col = w * 64 + j * 16 + lrow;
        dst[row * 256 + col] = acc[i][j][r];
      }
}

// ---- xpn[(b,kk)][u*256+c] = bf16( sum_kc xpp / rsum ) : GEMM A operand ----
__global__ __launch_bounds__(256) void k_xpn(const float* __restrict__ xpp,
    const float* __restrict__ rsum, unsigned short* __restrict__ xpn) {
  int b = blockIdx.x >> 4, kk = blockIdx.x & 15;
  int t = threadIdx.x;
  unsigned short* dst = xpn + ((size_t)(b * 16 + kk)) * 1024;
#pragma unroll
  for (int u = 0; u < 4; ++u) {
    int row = u * 16 + kk;
    float s = 0.f;
#pragma unroll
    for (int kc = 0; kc < 16; ++kc)
      s += xpp[((size_t)(b * 16 + kc) * UK + row) * CC + t];
    s /= rsum[b * UK + row];
    dst[u * 256 + t] = f2bf(s);
  }
}

// ---- wvs[ch][c] = bf16( AV[ch] * Wv[ch][c] ) : BN-scaled GEMM B operand ----
__global__ __launch_bounds__(256) void k_wvs(const float* __restrict__ Wv,
    const float* __restrict__ AV, unsigned short* __restrict__ wvs) {
  int ch = blockIdx.x;                   // 0..1023
  int t = threadIdx.x;
  float a = AV[ch];
  wvs[(size_t)ch * CC + t] = f2bf(a * Wv[(size_t)ch * CC + t]);
}

// ---- ctx[(b,kk)][vv] = xpn . wvs^T + cst[vv]  (MFMA, M=N=256, K=1024) ----
// grid 64 = 8 m-tiles x 8 n-tiles of 32x32; 1 wave/block; frags direct from L2
__global__ __launch_bounds__(64) void k_ctx2(const unsigned short* __restrict__ xpn,
    const unsigned short* __restrict__ wvs,
    const float* __restrict__ AV, const float* __restrict__ bv,
    const float* __restrict__ BVa, float* __restrict__ CTX) {
  int mt = blockIdx.x >> 3, nt = blockIdx.x & 7;
  int m0 = mt * 32, n0 = nt * 32;
  int l = threadIdx.x;
  int lrow = l & 15, lk8 = (l >> 4) * 8;

  f32x4 acc[2][2];
#pragma unroll
  for (int i = 0; i < 2; ++i)
#pragma unroll
    for (int j = 0; j < 2; ++j) acc[i][j] = (f32x4)0.f;

#pragma unroll 4
  for (int k0 = 0; k0 < 1024; k0 += 32) {
    int u = k0 >> 8, c0 = k0 & 255;
    s16x8 a0 = *(const s16x8*)&xpn[(size_t)(m0 + lrow) * 1024 + k0 + lk8];
    s16x8 a1 = *(const s16x8*)&xpn[(size_t)(m0 + 16 + lrow) * 1024 + k0 + lk8];
    s16x8 b0 = *(const s16x8*)&wvs[(size_t)(u * 256 + n0 + lrow) * CC + c0 + lk8];
    s16x8 b1 = *(const s16x8*)&wvs[(size_t)(u * 256 + n0 + 16 + lrow) * CC + c0 + lk8];
    acc[0][0] = __builtin_amdgcn_mfma_f32_16x16x32_bf16(a0, b0, acc[0][0], 0, 0, 0);
    acc[0][1] = __builtin_amdgcn_mfma_f32_16x16x32_bf16(a0, b1, acc[0][1], 0, 0, 0);
    acc[1][0] = __builtin_amdgcn_mfma_f32_16x16x32_bf16(a1, b0, acc[1][0], 0, 0, 0);
    acc[1][1] = __builtin_amdgcn_mfma_f32_16x16x32_bf16(a1, b1, acc[1][1], 0, 0, 0);
  }

  // per-column constant: cst[vv] = sum_u AV*bv + BVa
  float cst[2];
#pragma unroll
  for (int j = 0; j < 2; ++j) {
    int vv = n0 + j * 16 + lrow;
    float s = 0.f;
#pragma unroll
    for (int u = 0; u < 4; ++u) {
      int ch = u * 256 + vv;
      s += AV[ch] * bv[ch] + BVa[ch];
    }
    cst[j] = s;
  }

#pragma unroll
  for (int i = 0; i < 2; ++i)
#pragma unroll
    for (int j = 0; j < 2; ++j)
#pragma unroll
      for (int r = 0; r < 4; ++r) {
        int row = m0 + i * 16 + (l >> 4) * 4 + r;
        int col = n0 + j * 16 + lrow;
        CTX[(size_t)row * 256 + col] = acc[i][j][r] + cst[j];
      }
}

// ---------------- y[b,vv,m] = sum_kk (aQ*Q+bQ)[kk,m] * ctx[kk,vv] ----------------
__global__ __launch_bounds__(256) void k_y(const float* __restrict__ Qb,
    const float* __restrict__ CTX,
    const float* __restrict__ AQ, const float* __restrict__ BQa,
    float* __restrict__ y) {
  int b = blockIdx.x >> 4, nc = blockIdx.x & 15;
  int m = nc * 256 + threadIdx.x;
  float qn[16];
#pragma unroll
  for (int kk = 0; kk < 16; ++kk)
    qn[kk] = AQ[kk] * Qb[((size_t)b * KD + kk) * MM + m] + BQa[kk];
  const float* cb = CTX + (size_t)b * KD * 256;
  float* yo = y + (size_t)b * 256 * MM + m;
#pragma unroll 4
  for (int vv = 0; vv < 256; ++vv) {
    float acc = 0.f;
#pragma unroll
    for (int kk = 0; kk < 16; ++kk)
      acc = fmaf(qn[kk], cb[kk * 256 + vv], acc);
    yo[(size_t)vv * MM] = acc;
  }
}

extern "C" void kernel_launch(void* const* d_in, const int* in_sizes, int n_in,
                              void* d_out, int out_size, void* d_ws, size_t ws_size,
                              hipStream_t stream) {
  const float* x   = (const float*)d_in[0];
  const float* Wq  = (const float*)d_in[1];
  const float* bq  = (const float*)d_in[2];
  const float* Wk  = (const float*)d_in[3];
  const float* bk  = (const float*)d_in[4];
  const float* Wv  = (const float*)d_in[5];
  const float* bv  = (const float*)d_in[6];
  const float* gq  = (const float*)d_in[7];
  const float* btq = (const float*)d_in[8];
  const float* gv  = (const float*)d_in[9];
  const float* btv = (const float*)d_in[10];
  float* out = (float*)d_out;
  float* ws  = (float*)d_ws;

  // workspace layout (f32-element offsets) — no zero-init required anywhere
  float* G     = ws;                      // 65536            -> 65536
  float* XSUMP = ws + 65536;              // 4096             -> 69632
  float* RMAX  = ws + 69632;              // 1024             -> 70656
  float* RSUM  = ws + 70656;              // 1024             -> 71680
  float* AV    = ws + 71680;              // 1024             -> 72704
  float* BVa   = ws + 72704;              // 1024             -> 73728
  float* AQ    = ws + 73728;              // 16               -> 73744
  float* BQa   = ws + 73744;              // 16 (pad)         -> 73984
  float* CTX   = ws + 73984;              // 65536            -> 139520
  float* XPP   = ws + 139520;             // 4194304          -> 4333824
  float* KB    = ws + 4333824;            // 4194304          -> 8528128
  float* QB    = ws + 8528128;            // 1048576          -> 9576704
  u32*  PART   = (u32*)(ws + 139520);     // aliases XPP+KB (disjoint lifetime)
  unsigned short* XBF = (unsigned short*)(ws + 9576704);   // 16.8M bf16 -> ends 17965312
  unsigned short* XPN = (unsigned short*)(ws + 17965312);  // 262144 bf16 -> 18096384
  unsigned short* WVS = (unsigned short*)(ws + 18096384);  // 262144 bf16 -> 18227456 (~72.9 MB)

  k_cvt   <<<4096, 256, 0, stream>>>(x, XBF, XSUMP);
  k_gxx   <<<256,  512, 0, stream>>>(XBF, PART);
  k_gred  <<<128,  256, 0, stream>>>(PART, G);
  k_proj  <<<512,  256, 0, stream>>>(XBF, Wq, bq, Wk, bk, KB, QB);
  k_sstats<<<1024, 256, 0, stream>>>(KB, RMAX, RSUM);
  k_fin   <<<260,  256, 0, stream>>>(G, XSUMP, Wv, bv, gv, btv, Wq, bq, gq, btq,
                                     AV, BVa, AQ, BQa);
  k_xp    <<<256,  256, 0, stream>>>(XBF, KB, RMAX, XPP);
  k_xpn   <<<256,  256, 0, stream>>>(XPP, RSUM, XPN);
  k_wvs   <<<1024, 256, 0, stream>>>(Wv, AV, WVS);
  k_ctx2  <<<64,   64,  0, stream>>>(XPN, WVS, AV, bv, BVa, CTX);
  k_y     <<<256,  256, 0, stream>>>(QB, CTX, AQ, BQa, out);
}